// Round 2
// baseline (1158.721 us; speedup 1.0000x reference)
//
#include <hip/hip_runtime.h>

// ---------------------------------------------------------------------------
// Transformer block (Gemma-style) B=2,T=2048,D=2048,N=8,K=4,H=256,F=8192.
// fp32 in/out, fp16 MFMA internals.
// R5: R4 pipeline with two fixes:
//  (1) attn QK^T operand pairing: the swizzled Ks address already recovers
//      logical plane ks for every lane -> pair with qfrag[ks], NOT
//      qfrag[ks^kxr] (R4 bug: b2=1 lanes mixed planes -> absmax 9.3).
//  (2) pipelined GEMM barriers now asm("s_barrier":::"memory") — same HW op
//      (no waitcnt drain) but a compiler fence so global_load_lds staging
//      cannot be hoisted across the end-of-iter barrier into the window
//      where other waves still read that buffer.
// Structure: 256-row-tile, BK=64, 8-wave, 3-LDS-buffer pipeline, counted
// vmcnt(6) (never 0 in main loop), s_setprio around MFMA clusters,
// XOR chunk-swizzle staged via pre-swizzled global source, XCD swizzle.
// ---------------------------------------------------------------------------

typedef _Float16 h8 __attribute__((ext_vector_type(8)));
typedef _Float16 h4 __attribute__((ext_vector_type(4)));
typedef float f4 __attribute__((ext_vector_type(4)));

#define BDIM 2
#define TDIM 2048
#define DDIM 2048
#define NQ 8
#define NKV 4
#define HDIM 256
#define FDIM 8192
#define MROWS (BDIM * TDIM)   // 4096
#define WINDOW 1024
#define QS 4096               // combined qkv row stride

#define BAR() asm volatile("s_barrier" ::: "memory")

// gelu(x) = x * sigmoid(1.59577*(x + 0.044715 x^3)) (tanh form, exp-based)
__device__ __forceinline__ float gelu_fast(float x) {
  float u = 1.5957691216057308f * (x + 0.044715f * x * x * x);
  float e = __expf(u);
  return x * e / (e + 1.f);
}

// async global->LDS, 16B per lane; LDS dest is wave-uniform base + lane*16
__device__ __forceinline__ void g2l16(const _Float16* g, _Float16* l) {
  __builtin_amdgcn_global_load_lds(
      (const __attribute__((address_space(1))) void*)g,
      (__attribute__((address_space(3))) void*)l, 16, 0, 0);
}

__device__ inline float block_sum(float v, float* sbuf) {
#pragma unroll
  for (int off = 32; off; off >>= 1) v += __shfl_xor(v, off, 64);
  __syncthreads();
  if ((threadIdx.x & 63) == 0) sbuf[threadIdx.x >> 6] = v;
  __syncthreads();
  return sbuf[0] + sbuf[1] + sbuf[2] + sbuf[3];
}

// ---------------------------------------------------------------------------
// GEMM: C[M,Nc] = A[M,K](fp16) * Bt[Nc,K]^T (fp16).
// 256x128 block tile, BK=64, 512 threads (8 waves, 4M x 2N, 64x64/wave).
// 3 LDS tile-buffers (144KB): compute buf kt%3, stage kt+2 into (kt+2)%3,
// end-of-tile s_waitcnt vmcnt(6) (6 staging loads/wave/tile) -> tile kt+1
// forced complete, kt+2 stays in flight. Raw s_barrier (no drain).
// LDS swizzle: physical 16B-chunk = logical ^ (row&7); staged via
// pre-swizzled GLOBAL source col (LDS dest stays linear for gload_lds),
// read with per-lane-constant offsets -> conflict-free ds_read_b128.
// EPI: 0 = f32 store, 1 = fp16 store.
template <int EPI>
__global__ __launch_bounds__(512, 2) void gemm256(
    const _Float16* __restrict__ A, const _Float16* __restrict__ Bt,
    void* __restrict__ Cout, int M, int Nc, int K) {
  __shared__ _Float16 As[3][256 * 64];   // 96KB
  __shared__ _Float16 Bs[3][128 * 64];   // 48KB
  (void)M;
  const int tid = threadIdx.x;
  const int lane = tid & 63, w = tid >> 6;
  // bijective XCD swizzle (all launched grids are %8 == 0)
  const int nwg = gridDim.x;
  const int bid2 = (blockIdx.x & 7) * (nwg >> 3) + (blockIdx.x >> 3);
  const int nbx = Nc >> 7;
  const int bx = bid2 % nbx, by = bid2 / nbx;
  const int m0 = by * 256, n0 = bx * 128;
  const int wm = (w >> 1) * 64, wn = (w & 1) * 64;
  const int l16 = lane & 15, quad = lane >> 4;

  // staging: 8-row groups, global source col pre-swizzled by row&7
  const int lr = lane >> 3;                        // row within 8-row group
  const int swz8 = ((lane & 7) ^ lr) << 3;         // swizzled col (halves)
  const _Float16* Ag = A + (size_t)(m0 + w * 32 + lr) * K + swz8;
  const _Float16* Bg = Bt + (size_t)(n0 + w * 16 + lr) * K + swz8;

  // fragment reads: physical chunk = (ks*4+quad) ^ (row&7); row&7 == l16&7
  const int qs8 = (quad ^ (l16 & 3)) << 3;         // halves
  const int kxo = ((l16 >> 2) & 1) << 5;           // plane-0 phys offset
  int aoff[4], boff[4];
#pragma unroll
  for (int i = 0; i < 4; i++) {
    aoff[i] = (wm + i * 16 + l16) * 64 + qs8;
    boff[i] = (wn + i * 16 + l16) * 64 + qs8;
  }

  f4 acc[4][4];
#pragma unroll
  for (int i = 0; i < 4; i++)
#pragma unroll
    for (int j = 0; j < 4; j++) {
      acc[i][j][0] = 0.f; acc[i][j][1] = 0.f; acc[i][j][2] = 0.f; acc[i][j][3] = 0.f;
    }

#define SA(b, kt, c) g2l16(Ag + (size_t)(c) * 8 * K + (size_t)(kt) * 64, \
                           &As[b][(w * 32 + (c) * 8) * 64])
#define SB(b, kt, c) g2l16(Bg + (size_t)(c) * 8 * K + (size_t)(kt) * 64, \
                           &Bs[b][(w * 16 + (c) * 8) * 64])

  // prologue: tiles 0 (buf0) and 1 (buf1); force T0, leave T1 in flight
  SA(0, 0, 0); SA(0, 0, 1); SA(0, 0, 2); SA(0, 0, 3); SB(0, 0, 0); SB(0, 0, 1);
  SA(1, 1, 0); SA(1, 1, 1); SA(1, 1, 2); SA(1, 1, 3); SB(1, 1, 0); SB(1, 1, 1);
  asm volatile("s_waitcnt vmcnt(6)" ::: "memory");
  BAR();

  const int nt = K >> 6;
  for (int kt = 0; kt < nt; ++kt) {
    const int cur = kt % 3, nb = (kt + 2) % 3;
    const bool pf = (kt + 2) < nt;
    const _Float16* Ab = As[cur];
    const _Float16* Bb = Bs[cur];
    h8 af[4][2], bf[4][2];
    // ---- phase 1: mi0-3 x ni0-1 ----
#pragma unroll
    for (int i = 0; i < 4; i++) {
      af[i][0] = *(const h8*)&Ab[aoff[i] + kxo];
      af[i][1] = *(const h8*)&Ab[aoff[i] + (kxo ^ 32)];
    }
#pragma unroll
    for (int i = 0; i < 2; i++) {
      bf[i][0] = *(const h8*)&Bb[boff[i] + kxo];
      bf[i][1] = *(const h8*)&Bb[boff[i] + (kxo ^ 32)];
    }
    if (pf) { SA(nb, kt + 2, 0); SA(nb, kt + 2, 1); SA(nb, kt + 2, 2); }
    BAR();
    __builtin_amdgcn_s_setprio(1);
#pragma unroll
    for (int mi = 0; mi < 4; mi++)
#pragma unroll
      for (int ni = 0; ni < 2; ni++)
#pragma unroll
        for (int ks = 0; ks < 2; ks++)
          acc[mi][ni] = __builtin_amdgcn_mfma_f32_16x16x32_f16(
              af[mi][ks], bf[ni][ks], acc[mi][ni], 0, 0, 0);
    __builtin_amdgcn_s_setprio(0);
    BAR();
    // ---- phase 2: mi0-3 x ni2-3 ----
#pragma unroll
    for (int i = 2; i < 4; i++) {
      bf[i][0] = *(const h8*)&Bb[boff[i] + kxo];
      bf[i][1] = *(const h8*)&Bb[boff[i] + (kxo ^ 32)];
    }
    if (pf) { SA(nb, kt + 2, 3); SB(nb, kt + 2, 0); SB(nb, kt + 2, 1); }
    BAR();
    __builtin_amdgcn_s_setprio(1);
#pragma unroll
    for (int mi = 0; mi < 4; mi++)
#pragma unroll
      for (int ni = 2; ni < 4; ni++)
#pragma unroll
        for (int ks = 0; ks < 2; ks++)
          acc[mi][ni] = __builtin_amdgcn_mfma_f32_16x16x32_f16(
              af[mi][ks], bf[ni][ks], acc[mi][ni], 0, 0, 0);
    __builtin_amdgcn_s_setprio(0);
    if (pf)                 asm volatile("s_waitcnt vmcnt(6)" ::: "memory");
    else if (kt + 2 == nt)  asm volatile("s_waitcnt vmcnt(0)" ::: "memory");
    BAR();
  }
#undef SA
#undef SB

#pragma unroll
  for (int mi = 0; mi < 4; mi++)
#pragma unroll
    for (int ni = 0; ni < 4; ni++)
#pragma unroll
      for (int r = 0; r < 4; r++) {
        const int rg = m0 + wm + mi * 16 + quad * 4 + r;
        const int cg = n0 + wn + ni * 16 + l16;
        const size_t idx = (size_t)rg * Nc + cg;
        if (EPI == 0) ((float*)Cout)[idx] = acc[mi][ni][r];
        else          ((_Float16*)Cout)[idx] = (_Float16)acc[mi][ni][r];
      }
}

// ---------------------------------------------------------------------------
// dual-B gating GEMM: act = gelu(A*B0^T) * (A*B1^T), fp16 out.
// 256x64 block tile, BK=64, 8 waves (4M x 2N, 64x32/wave, dual acc).
// Same 3-buffer counted-vmcnt pipeline + swizzle as gemm256.
__global__ __launch_bounds__(512, 2) void gemm_gate256(
    const _Float16* __restrict__ A, const _Float16* __restrict__ B0,
    const _Float16* __restrict__ B1, _Float16* __restrict__ act,
    int M, int Nc, int K) {
  __shared__ _Float16 As[3][256 * 64];    // 96KB
  __shared__ _Float16 B0s[3][64 * 64];    // 24KB
  __shared__ _Float16 B1s[3][64 * 64];    // 24KB
  (void)M;
  const int tid = threadIdx.x;
  const int lane = tid & 63, w = tid >> 6;
  const int nwg = gridDim.x;
  const int bid2 = (blockIdx.x & 7) * (nwg >> 3) + (blockIdx.x >> 3);
  const int nbx = Nc >> 6;
  const int bx = bid2 % nbx, by = bid2 / nbx;
  const int m0 = by * 256, n0 = bx * 64;
  const int wm = (w >> 1) * 64, wn = (w & 1) * 32;
  const int l16 = lane & 15, quad = lane >> 4;

  const int lr = lane >> 3;
  const int swz8 = ((lane & 7) ^ lr) << 3;
  const _Float16* Ag  = A  + (size_t)(m0 + w * 32 + lr) * K + swz8;
  const _Float16* B0g = B0 + (size_t)(n0 + w * 8 + lr) * K + swz8;
  const _Float16* B1g = B1 + (size_t)(n0 + w * 8 + lr) * K + swz8;

  const int qs8 = (quad ^ (l16 & 3)) << 3;
  const int kxo = ((l16 >> 2) & 1) << 5;
  int aoff[4], boff[2];
#pragma unroll
  for (int i = 0; i < 4; i++) aoff[i] = (wm + i * 16 + l16) * 64 + qs8;
#pragma unroll
  for (int i = 0; i < 2; i++) boff[i] = (wn + i * 16 + l16) * 64 + qs8;

  f4 acc0[4][2], acc1[4][2];
#pragma unroll
  for (int i = 0; i < 4; i++)
#pragma unroll
    for (int j = 0; j < 2; j++) {
      acc0[i][j][0] = 0.f; acc0[i][j][1] = 0.f; acc0[i][j][2] = 0.f; acc0[i][j][3] = 0.f;
      acc1[i][j][0] = 0.f; acc1[i][j][1] = 0.f; acc1[i][j][2] = 0.f; acc1[i][j][3] = 0.f;
    }

#define SA(b, kt, c) g2l16(Ag + (size_t)(c) * 8 * K + (size_t)(kt) * 64, \
                           &As[b][(w * 32 + (c) * 8) * 64])
#define SB0(b, kt) g2l16(B0g + (size_t)(kt) * 64, &B0s[b][w * 8 * 64])
#define SB1(b, kt) g2l16(B1g + (size_t)(kt) * 64, &B1s[b][w * 8 * 64])

  SA(0, 0, 0); SA(0, 0, 1); SA(0, 0, 2); SA(0, 0, 3); SB0(0, 0); SB1(0, 0);
  SA(1, 1, 0); SA(1, 1, 1); SA(1, 1, 2); SA(1, 1, 3); SB0(1, 1); SB1(1, 1);
  asm volatile("s_waitcnt vmcnt(6)" ::: "memory");
  BAR();

  const int nt = K >> 6;
  for (int kt = 0; kt < nt; ++kt) {
    const int cur = kt % 3, nb = (kt + 2) % 3;
    const bool pf = (kt + 2) < nt;
    const _Float16* Ab = As[cur];
    const _Float16* Bb0 = B0s[cur];
    const _Float16* Bb1 = B1s[cur];
    h8 af[4][2], b0f[2][2], b1f[2][2];
    // ---- phase 1: acc0 (gate) ----
#pragma unroll
    for (int i = 0; i < 4; i++) {
      af[i][0] = *(const h8*)&Ab[aoff[i] + kxo];
      af[i][1] = *(const h8*)&Ab[aoff[i] + (kxo ^ 32)];
    }
#pragma unroll
    for (int i = 0; i < 2; i++) {
      b0f[i][0] = *(const h8*)&Bb0[boff[i] + kxo];
      b0f[i][1] = *(const h8*)&Bb0[boff[i] + (kxo ^ 32)];
    }
    if (pf) { SA(nb, kt + 2, 0); SA(nb, kt + 2, 1); SA(nb, kt + 2, 2); }
    BAR();
    __builtin_amdgcn_s_setprio(1);
#pragma unroll
    for (int mi = 0; mi < 4; mi++)
#pragma unroll
      for (int ni = 0; ni < 2; ni++)
#pragma unroll
        for (int ks = 0; ks < 2; ks++)
          acc0[mi][ni] = __builtin_amdgcn_mfma_f32_16x16x32_f16(
              af[mi][ks], b0f[ni][ks], acc0[mi][ni], 0, 0, 0);
    __builtin_amdgcn_s_setprio(0);
    BAR();
    // ---- phase 2: acc1 (mult) ----
#pragma unroll
    for (int i = 0; i < 2; i++) {
      b1f[i][0] = *(const h8*)&Bb1[boff[i] + kxo];
      b1f[i][1] = *(const h8*)&Bb1[boff[i] + (kxo ^ 32)];
    }
    if (pf) { SA(nb, kt + 2, 3); SB0(nb, kt + 2); SB1(nb, kt + 2); }
    BAR();
    __builtin_amdgcn_s_setprio(1);
#pragma unroll
    for (int mi = 0; mi < 4; mi++)
#pragma unroll
      for (int ni = 0; ni < 2; ni++)
#pragma unroll
        for (int ks = 0; ks < 2; ks++)
          acc1[mi][ni] = __builtin_amdgcn_mfma_f32_16x16x32_f16(
              af[mi][ks], b1f[ni][ks], acc1[mi][ni], 0, 0, 0);
    __builtin_amdgcn_s_setprio(0);
    if (pf)                 asm volatile("s_waitcnt vmcnt(6)" ::: "memory");
    else if (kt + 2 == nt)  asm volatile("s_waitcnt vmcnt(0)" ::: "memory");
    BAR();
  }
#undef SA
#undef SB0
#undef SB1

#pragma unroll
  for (int mi = 0; mi < 4; mi++)
#pragma unroll
    for (int ni = 0; ni < 2; ni++)
#pragma unroll
      for (int r = 0; r < 4; r++) {
        const int rg = m0 + wm + mi * 16 + quad * 4 + r;
        const int cg = n0 + wn + ni * 16 + l16;
        act[(size_t)rg * Nc + cg] =
            (_Float16)(gelu_fast(acc0[mi][ni][r]) * acc1[mi][ni][r]);
      }
}

// ------------- transpose + cast f32 [R,C] -> fp16 [C,R], per-z slab --------
__global__ __launch_bounds__(256) void transpose_cast_kernel(
    const float* __restrict__ in, _Float16* __restrict__ out,
    int R, int C, size_t in_zstride, size_t out_zstride) {
  __shared__ float tile[64][65];
  const float* ip = in + blockIdx.z * in_zstride;
  _Float16* op = out + blockIdx.z * out_zstride;
  const int cb = blockIdx.x * 64, rb = blockIdx.y * 64;
  const int tx = threadIdx.x & 15, ty = threadIdx.x >> 4;
#pragma unroll
  for (int i = 0; i < 4; i++) {
    f4 v = *(const f4*)&ip[(size_t)(rb + ty + 16 * i) * C + cb + tx * 4];
    tile[ty + 16 * i][tx * 4 + 0] = v[0];
    tile[ty + 16 * i][tx * 4 + 1] = v[1];
    tile[ty + 16 * i][tx * 4 + 2] = v[2];
    tile[ty + 16 * i][tx * 4 + 3] = v[3];
  }
  __syncthreads();
#pragma unroll
  for (int i = 0; i < 4; i++) {
    const int c = ty + 16 * i;
    h4 o;
#pragma unroll
    for (int j = 0; j < 4; j++) o[j] = (_Float16)tile[tx * 4 + j][c];
    *(h4*)&op[(size_t)(cb + c) * R + rb + tx * 4] = o;
  }
}

// ----------------------------- f32 -> fp16 cast ----------------------------
__global__ void cast_fp16_kernel(const float* __restrict__ in,
                                 _Float16* __restrict__ out, int n4) {
  int i = blockIdx.x * 256 + threadIdx.x;
  if (i < n4) {
    f4 v = ((const f4*)in)[i];
    h4 o;
    o[0] = (_Float16)v[0]; o[1] = (_Float16)v[1];
    o[2] = (_Float16)v[2]; o[3] = (_Float16)v[3];
    ((h4*)out)[i] = o;
  }
}

// -------------------- RMS-norm over 2048-row -> fp16 out -------------------
__global__ __launch_bounds__(256) void rmsnorm_fp16_kernel(
    const float* __restrict__ in, const float* __restrict__ scale,
    _Float16* __restrict__ out) {
  __shared__ float sbuf[4];
  const int row = blockIdx.x, tid = threadIdx.x;
  const float* r = in + (size_t)row * 2048;
  f4 a = ((const f4*)r)[tid];
  f4 b = ((const f4*)r)[tid + 256];
  float ss = a[0]*a[0] + a[1]*a[1] + a[2]*a[2] + a[3]*a[3] +
             b[0]*b[0] + b[1]*b[1] + b[2]*b[2] + b[3]*b[3];
  float tot = block_sum(ss, sbuf);
  float rs = rsqrtf(tot * (1.f / 2048.f) + 1e-6f);
  f4 s0 = ((const f4*)scale)[tid];
  f4 s1 = ((const f4*)scale)[tid + 256];
  h4 o0, o1;
#pragma unroll
  for (int j = 0; j < 4; j++) {
    o0[j] = (_Float16)(a[j] * rs * (1.f + s0[j]));
    o1[j] = (_Float16)(b[j] * rs * (1.f + s1[j]));
  }
  ((h4*)(out + (size_t)row * 2048))[tid] = o0;
  ((h4*)(out + (size_t)row * 2048))[tid + 256] = o1;
}

// --- fused per-head norm/RoPE over combined qkv rows (fp16 in, fp16 out) ---
__global__ __launch_bounds__(256) void headnorm_qkv_kernel(
    const _Float16* __restrict__ qkv, _Float16* __restrict__ out,
    const float* __restrict__ qsc, const float* __restrict__ ksc,
    const int* __restrict__ pos_arr) {
  const int inst = blockIdx.x * 4 + (threadIdx.x >> 6);
  const int lane = threadIdx.x & 63;
  const int row = inst >> 4, slot = inst & 15;
  const _Float16* r = qkv + (size_t)row * QS + slot * 256;
  h4 vh = ((const h4*)r)[lane];
  f4 v;
#pragma unroll
  for (int j = 0; j < 4; j++) v[j] = (float)vh[j];
  float ss = v[0]*v[0] + v[1]*v[1] + v[2]*v[2] + v[3]*v[3];
#pragma unroll
  for (int off = 32; off; off >>= 1) ss += __shfl_xor(ss, off, 64);
  const float rs = rsqrtf(ss * (1.f / 256.f) + 1e-6f);
  const float* scale = (slot < 8) ? qsc : (slot < 12 ? ksc : nullptr);
  f4 nv;
  if (scale) {
    f4 sc = ((const f4*)scale)[lane];
#pragma unroll
    for (int j = 0; j < 4; j++) nv[j] = v[j] * rs * (1.f + sc[j]);
  } else {
#pragma unroll
    for (int j = 0; j < 4; j++) nv[j] = v[j] * rs;
  }
  h4 res;
  if (slot < 12) {  // rope for q and k
    const float pos = (float)pos_arr[row];
    const bool lo = lane < 32;
#pragma unroll
    for (int j = 0; j < 4; j++) {
      float partner = __shfl_xor(nv[j], 32, 64);
      const int ph = (lane * 4 + j) & 127;
      float it = exp2f((float)ph * -0.103810253f);  // 10000^(-p/128)
      float ang = pos * it;
      float sn, cs;
      sincosf(ang, &sn, &cs);
      res[j] = (_Float16)(lo ? (nv[j] * cs - partner * sn)
                             : (nv[j] * cs + partner * sn));
    }
  } else {
#pragma unroll
    for (int j = 0; j < 4; j++) res[j] = (_Float16)nv[j];
  }
  ((h4*)(out + (size_t)row * QS + slot * 256))[lane] = res;
}

// ---- transpose V slots of qkvh: [row][3072+kvh*256+h] -> vT[b,kvh,h,t] ----
__global__ __launch_bounds__(256) void transpose_v_kernel(
    const _Float16* __restrict__ qkvh, _Float16* __restrict__ vT) {
  __shared__ _Float16 tile[32][33];
  const int z = blockIdx.z;
  const int b = z >> 2, kvh = z & 3;
  const int tb = blockIdx.x * 32, hb = blockIdx.y * 32;
  const int x = threadIdx.x, y = threadIdx.y;
#pragma unroll
  for (int i = 0; i < 4; i++)
    tile[y + 8 * i][x] =
        qkvh[(size_t)(b * TDIM + tb + y + 8 * i) * QS + 3072 + kvh * 256 + hb + x];
  __syncthreads();
#pragma unroll
  for (int i = 0; i < 4; i++)
    vT[((size_t)z * HDIM + hb + y + 8 * i) * TDIM + tb + x] = tile[x][y + 8 * i];
}

// --------------------- flash attention, 64 q-rows / block ------------------
// Ks [32][256]h (512B rows) and Vs [256][32]h (64B rows) XOR-chunk-swizzled.
// NOTE: the swizzled Ks read address recovers logical plane ks for EVERY
// lane, so the MFMA pairs qfrag[ks] (R4 paired qfrag[ks^kxr] — wrong).
__global__ __launch_bounds__(256) void attn_kernel(
    const _Float16* __restrict__ qkvh, const _Float16* __restrict__ vT,
    _Float16* __restrict__ enc) {
  __shared__ _Float16 Ks[32 * 256];
  __shared__ _Float16 Vs[256 * 32];
  __shared__ _Float16 Ps[4][16 * 32];
  const int t0 = blockIdx.x * 64;
  const int n = blockIdx.y;
  const int b = blockIdx.z;
  const int kvh = n >> 1;
  const int tid = threadIdx.x;
  const int w = tid >> 6, lane = tid & 63, l16 = lane & 15, quad = lane >> 4;
  const int kxr = (l16 >> 2) & 1;                  // Ks ks-plane phys xor
  const int qsK8 = (quad ^ (l16 & 3)) << 3;        // Ks chunk swizzle (halves)
  const int qsV8 = (quad ^ ((l16 >> 1) & 3)) << 3; // Vs chunk swizzle (halves)

  h8 qfrag[8];
  {
    const int trow = t0 + w * 16 + l16;
    const _Float16* qp =
        qkvh + (size_t)(b * TDIM + trow) * QS + n * HDIM + quad * 8;
#pragma unroll
    for (int ks = 0; ks < 8; ks++) qfrag[ks] = *(const h8*)(qp + ks * 32);
  }

  f4 O[16];
#pragma unroll
  for (int i = 0; i < 16; i++) { O[i][0] = 0.f; O[i][1] = 0.f; O[i][2] = 0.f; O[i][3] = 0.f; }
  float m_i[4], l_i[4];
#pragma unroll
  for (int r = 0; r < 4; r++) { m_i[r] = -1e30f; l_i[r] = 0.f; }

  int s_begin = t0 - (WINDOW - 1);
  if (s_begin < 0) s_begin = 0;
  s_begin &= ~31;
  const int s_end = t0 + 64;
  const _Float16* kbase = qkvh + (size_t)b * TDIM * QS + 2048 + kvh * HDIM;
  const _Float16* vbase = vT + ((size_t)(b * NKV + kvh) * HDIM) * TDIM;

  for (int s0 = s_begin; s0 < s_end; s0 += 32) {
    __syncthreads();
#pragma unroll
    for (int p = 0; p < 4; p++) {
      int g = p * 256 + tid;
      {
        int si = g >> 5, c = g & 31;
        *(h8*)&Ks[si * 256 + ((c ^ (si & 7)) << 3)] =
            *(const h8*)(kbase + (size_t)(s0 + si) * QS + (c << 3));
      }
      {
        int h = g >> 2, c = g & 3;
        *(h8*)&Vs[h * 32 + ((c ^ ((g >> 3) & 3)) << 3)] =
            *(const h8*)(vbase + (size_t)h * TDIM + s0 + (c << 3));
      }
    }
    __syncthreads();

    float P[2][4], cmax[4];
#pragma unroll
    for (int r = 0; r < 4; r++) cmax[r] = -1e30f;
#pragma unroll
    for (int sc = 0; sc < 2; sc++) {
      f4 lg; lg[0] = 0.f; lg[1] = 0.f; lg[2] = 0.f; lg[3] = 0.f;
#pragma unroll
      for (int ks = 0; ks < 8; ks++) {
        h8 kb = *(const h8*)&Ks[(sc * 16 + l16) * 256 + ((ks ^ kxr) << 5) + qsK8];
        lg = __builtin_amdgcn_mfma_f32_16x16x32_f16(qfrag[ks], kb, lg, 0, 0, 0);
      }
      const int scol = s0 + sc * 16 + l16;
#pragma unroll
      for (int r = 0; r < 4; r++) {
        const int trow = t0 + w * 16 + quad * 4 + r;
        // 50*tanh(lg/50): tanh(y)=(e^2y-1)/(e^2y+1), e^2y = expf(lg*0.04)
        float t = __expf(lg[r] * 0.04f);
        float xv = 50.f - 100.f * __builtin_amdgcn_rcpf(t + 1.f);
        bool valid = (scol <= trow) && (scol > trow - WINDOW);
        P[sc][r] = valid ? xv : -1e30f;
        cmax[r] = fmaxf(cmax[r], P[sc][r]);
      }
    }
#pragma unroll
    for (int off = 1; off < 16; off <<= 1)
#pragma unroll
      for (int r = 0; r < 4; r++) cmax[r] = fmaxf(cmax[r], __shfl_xor(cmax[r], off, 16));
    float alpha[4], psum[4];
#pragma unroll
    for (int r = 0; r < 4; r++) {
      float mnew = fmaxf(m_i[r], cmax[r]);
      alpha[r] = __expf(m_i[r] - mnew);
      m_i[r] = mnew;
      psum[r] = 0.f;
    }
#pragma unroll
    for (int sc = 0; sc < 2; sc++)
#pragma unroll
      for (int r = 0; r < 4; r++) {
        float pv = __expf(P[sc][r] - m_i[r]);
        P[sc][r] = pv;
        psum[r] += pv;
      }
#pragma unroll
    for (int off = 1; off < 16; off <<= 1)
#pragma unroll
      for (int r = 0; r < 4; r++) psum[r] += __shfl_xor(psum[r], off, 16);
#pragma unroll
    for (int r = 0; r < 4; r++) l_i[r] = l_i[r] * alpha[r] + psum[r];
#pragma unroll
    for (int i = 0; i < 16; i++)
#pragma unroll
      for (int r = 0; r < 4; r++) O[i][r] *= alpha[r];
#pragma unroll
    for (int sc = 0; sc < 2; sc++)
#pragma unroll
      for (int r = 0; r < 4; r++)
        Ps[w][(quad * 4 + r) * 32 + sc * 16 + l16] = (_Float16)P[sc][r];
    h8 pa = *(const h8*)&Ps[w][l16 * 32 + quad * 8];
#pragma unroll
    for (int ht = 0; ht < 16; ht++) {
      h8 vb = *(const h8*)&Vs[(ht * 16 + l16) * 32 + qsV8];
      O[ht] = __builtin_amdgcn_mfma_f32_16x16x32_f16(pa, vb, O[ht], 0, 0, 0);
    }
  }

  float invl[4];
#pragma unroll
  for (int r = 0; r < 4; r++) invl[r] = 1.f / l_i[r];
#pragma unroll
  for (int ht = 0; ht < 16; ht++)
#pragma unroll
    for (int r = 0; r < 4; r++) {
      const int trow = t0 + w * 16 + quad * 4 + r;
      enc[((size_t)(b * TDIM + trow)) * (NQ * HDIM) + n * HDIM + ht * 16 + l16] =
          (_Float16)(O[ht][r] * invl[r]);
    }
}

// ------ post-attn: residual + norm, then pre-FFW norm (fused) --------------
__global__ __launch_bounds__(256) void postattn_kernel(
    const float* __restrict__ attnraw, const float* __restrict__ x,
    const float* __restrict__ post_scale, const float* __restrict__ pre_ffw_scale,
    const float* __restrict__ skip, float* __restrict__ attn_out,
    _Float16* __restrict__ ffw_in) {
  __shared__ float sbuf[4];
  const int row = blockIdx.x, tid = threadIdx.x;
  const float* ar = attnraw + (size_t)row * 2048;
  const float* xr = x + (size_t)row * 2048;
  f4 a0 = ((const f4*)ar)[tid], a1 = ((const f4*)ar)[tid + 256];
  float ss = a0[0]*a0[0] + a0[1]*a0[1] + a0[2]*a0[2] + a0[3]*a0[3] +
             a1[0]*a1[0] + a1[1]*a1[1] + a1[2]*a1[2] + a1[3]*a1[3];
  float tot = block_sum(ss, sbuf);
  float rs = rsqrtf(tot * (1.f / 2048.f) + 1e-6f);
  const float sk = skip[0];
  f4 x0 = ((const f4*)xr)[tid], x1 = ((const f4*)xr)[tid + 256];
  f4 p0 = ((const f4*)post_scale)[tid], p1 = ((const f4*)post_scale)[tid + 256];
  f4 at0, at1;
#pragma unroll
  for (int j = 0; j < 4; j++) {
    at0[j] = x0[j] * sk + a0[j] * rs * (1.f + p0[j]);
    at1[j] = x1[j] * sk + a1[j] * rs * (1.f + p1[j]);
  }
  ((f4*)(attn_out + (size_t)row * 2048))[tid] = at0;
  ((f4*)(attn_out + (size_t)row * 2048))[tid + 256] = at1;
  float ss2 = at0[0]*at0[0] + at0[1]*at0[1] + at0[2]*at0[2] + at0[3]*at0[3] +
              at1[0]*at1[0] + at1[1]*at1[1] + at1[2]*at1[2] + at1[3]*at1[3];
  float tot2 = block_sum(ss2, sbuf);
  float rs2 = rsqrtf(tot2 * (1.f / 2048.f) + 1e-6f);
  f4 f0 = ((const f4*)pre_ffw_scale)[tid], f1 = ((const f4*)pre_ffw_scale)[tid + 256];
  h4 o0, o1;
#pragma unroll
  for (int j = 0; j < 4; j++) {
    o0[j] = (_Float16)(at0[j] * rs2 * (1.f + f0[j]));
    o1[j] = (_Float16)(at1[j] * rs2 * (1.f + f1[j]));
  }
  ((h4*)(ffw_in + (size_t)row * 2048))[tid] = o0;
  ((h4*)(ffw_in + (size_t)row * 2048))[tid + 256] = o1;
}

// ------ final: out = attn_out + rmsnorm(ffw_fp16, post_ffw_scale) ----------
__global__ __launch_bounds__(256) void final_kernel(
    const _Float16* __restrict__ ffw, const float* __restrict__ attn_out,
    const float* __restrict__ post_ffw_scale, float* __restrict__ out) {
  __shared__ float sbuf[4];
  const int row = blockIdx.x, tid = threadIdx.x;
  const _Float16* fr = ffw + (size_t)row * 2048;
  const float* ar = attn_out + (size_t)row * 2048;
  h4 fh0 = ((const h4*)fr)[tid], fh1 = ((const h4*)fr)[tid + 256];
  f4 a0, a1;
#pragma unroll
  for (int j = 0; j < 4; j++) { a0[j] = (float)fh0[j]; a1[j] = (float)fh1[j]; }
  float ss = a0[0]*a0[0] + a0[1]*a0[1] + a0[2]*a0[2] + a0[3]*a0[3] +
             a1[0]*a1[0] + a1[1]*a1[1] + a1[2]*a1[2] + a1[3]*a1[3];
  float tot = block_sum(ss, sbuf);
  float rs = rsqrtf(tot * (1.f / 2048.f) + 1e-6f);
  f4 s0 = ((const f4*)post_ffw_scale)[tid], s1 = ((const f4*)post_ffw_scale)[tid + 256];
  f4 x0 = ((const f4*)ar)[tid], x1 = ((const f4*)ar)[tid + 256];
  f4 o0, o1;
#pragma unroll
  for (int j = 0; j < 4; j++) {
    o0[j] = x0[j] + a0[j] * rs * (1.f + s0[j]);
    o1[j] = x1[j] + a1[j] * rs * (1.f + s1[j]);
  }
  ((f4*)(out + (size_t)row * 2048))[tid] = o0;
  ((f4*)(out + (size_t)row * 2048))[tid + 256] = o1;
}

// ---------------------------------------------------------------------------
extern "C" void kernel_launch(void* const* d_in, const int* in_sizes, int n_in,
                              void* d_out, int out_size, void* d_ws, size_t ws_size,
                              hipStream_t stream) {
  (void)in_sizes; (void)n_in; (void)out_size; (void)ws_size;
  const float* x              = (const float*)d_in[0];
  const int*   segment_pos    = (const int*)d_in[1];
  const float* w_q            = (const float*)d_in[7];
  const float* w_kv           = (const float*)d_in[8];
  const float* w_attn_vec     = (const float*)d_in[9];
  const float* q_norm_scale   = (const float*)d_in[10];
  const float* k_norm_scale   = (const float*)d_in[11];
  const float* pre_attn_scale = (const float*)d_in[12];
  const float* post_attn_scale= (const float*)d_in[13];
  const float* pre_ffw_scale  = (const float*)d_in[14];
  const float* post_ffw_scale = (const float*)d_in[15];
  const float* w_gating       = (const float*)d_in[16];
  const float* w_linear       = (const float*)d_in[17];
  const float* skip_scale     = (const float*)d_in[18];

  char* ws = (char*)d_ws;
  const size_t MB = 1024 * 1024;
  // weight arena [0,64MB): Wqkv (16MB) -> Wo (8MB) -> Wg (64MB) -> Wl (32MB)
  _Float16* Wqkv  = (_Float16*)(ws + 0);
  _Float16* Wo    = (_Float16*)(ws + 0);
  _Float16* Wg    = (_Float16*)(ws + 0);
  _Float16* Wl    = (_Float16*)(ws + 0);
  _Float16* Hbf   = (_Float16*)(ws + 64 * MB);   // 16MB: h, later ffw_in
  float* attnF    = (float*)(ws + 80 * MB);      // 32MB residual
  _Float16* qkvraw= (_Float16*)(ws + 112 * MB);  // 32MB [4096][4096] fp16
  _Float16* qkvh  = (_Float16*)(ws + 144 * MB);  // 32MB
  _Float16* enc   = (_Float16*)(ws + 176 * MB);  // 16MB
  float* attnraw  = (float*)(ws + 192 * MB);     // 32MB
  _Float16* vT    = (_Float16*)(ws + 224 * MB);  //  8MB
  _Float16* act   = (_Float16*)(ws + 112 * MB);  // 64MB (qkvraw/qkvh dead)
  _Float16* ffw   = (_Float16*)(ws + 192 * MB);  // 16MB (attnraw dead)
  float* outp     = (float*)d_out;

  // --- weight prep: per-head [D,H]->[H,D], stacked q|k|v into Wqkv ---
  transpose_cast_kernel<<<dim3(HDIM / 64, DDIM / 64, NQ), 256, 0, stream>>>(
      w_q, Wqkv, DDIM, HDIM, (size_t)DDIM * HDIM, (size_t)HDIM * DDIM);
  transpose_cast_kernel<<<dim3(HDIM / 64, DDIM / 64, NKV), 256, 0, stream>>>(
      w_kv, Wqkv + (size_t)2048 * DDIM, DDIM, HDIM,
      (size_t)DDIM * HDIM, (size_t)HDIM * DDIM);
  transpose_cast_kernel<<<dim3(HDIM / 64, DDIM / 64, NKV), 256, 0, stream>>>(
      w_kv + (size_t)NKV * DDIM * HDIM, Wqkv + (size_t)3072 * DDIM, DDIM, HDIM,
      (size_t)DDIM * HDIM, (size_t)HDIM * DDIM);
  // --- h = rmsnorm(x, pre_attn_scale) ---
  rmsnorm_fp16_kernel<<<MROWS, 256, 0, stream>>>(x, pre_attn_scale, Hbf);
  // --- fused QKV projection (fp16 out): 512 wgs ---
  gemm256<1><<<dim3((QS / 128) * (MROWS / 256)), 512, 0, stream>>>(
      Hbf, Wqkv, qkvraw, MROWS, QS, DDIM);
  // --- fused per-head norms + RoPE over all 16 head-slots ---
  headnorm_qkv_kernel<<<(MROWS * 16) / 4, 256, 0, stream>>>(
      qkvraw, qkvh, q_norm_scale, k_norm_scale, segment_pos);
  transpose_v_kernel<<<dim3(TDIM / 32, HDIM / 32, BDIM * NKV), dim3(32, 8), 0, stream>>>(
      qkvh, vT);
  // --- attention ---
  attn_kernel<<<dim3(TDIM / 64, NQ, BDIM), 256, 0, stream>>>(qkvh, vT, enc);
  // --- output projection: 256 wgs ---
  transpose_cast_kernel<<<dim3(DDIM / 64, (NQ * HDIM) / 64, 1), 256, 0, stream>>>(
      w_attn_vec, Wo, NQ * HDIM, DDIM, 0, 0);
  gemm256<0><<<dim3((DDIM / 128) * (MROWS / 256)), 512, 0, stream>>>(
      enc, Wo, attnraw, MROWS, DDIM, NQ * HDIM);
  // --- post-attn norm + residual, pre-FFW norm ---
  postattn_kernel<<<MROWS, 256, 0, stream>>>(attnraw, x, post_attn_scale,
                                             pre_ffw_scale, skip_scale, attnF, Hbf);
  // --- FFN: fused dual-gating GEMM with gelu*mult epilogue: 2048 wgs ---
  cast_fp16_kernel<<<(2 * FDIM * DDIM / 4 + 255) / 256, 256, 0, stream>>>(
      w_gating, Wg, 2 * FDIM * DDIM / 4);
  gemm_gate256<<<dim3((FDIM / 64) * (MROWS / 256)), 512, 0, stream>>>(
      Hbf, Wg, Wg + (size_t)FDIM * DDIM, act, MROWS, FDIM, DDIM);
  // --- linear (fp16 out): 256 wgs ---
  transpose_cast_kernel<<<dim3(DDIM / 64, FDIM / 64, 1), 256, 0, stream>>>(
      w_linear, Wl, FDIM, DDIM, 0, 0);
  gemm256<1><<<dim3((DDIM / 128) * (MROWS / 256)), 512, 0, stream>>>(
      act, Wl, ffw, MROWS, DDIM, FDIM);
  // --- final norm + residual ---
  final_kernel<<<MROWS, 256, 0, stream>>>(ffw, attnF, post_ffw_scale, outp);
}

// Round 3
// 1146.990 us; speedup vs baseline: 1.0102x; 1.0102x over previous
//
#include <hip/hip_runtime.h>

// ---------------------------------------------------------------------------
// Transformer block (Gemma-style) B=2,T=2048,D=2048,N=8,K=4,H=256,F=8192.
// fp32 in/out, fp16 MFMA internals.
// R6: gate GEMM rebuilt for TRAFFIC, not schedule: 256x128 dual-B tile
//     (halves per-pass staged bytes 3GB->2GB), double-buffered BK=64,
//     M-fastest-within-XCD-chunk ordering so the 1MB B0+B1 panel pair is
//     L2-resident (B traffic -> compulsory only). Stage for tile kt+1
//     issued at top of iter kt (full-iter slack), one vmcnt(0)/iter.
//     gemm256 (qkv/out/linear), attn, norms: unchanged from R5 (passing).
// ---------------------------------------------------------------------------

typedef _Float16 h8 __attribute__((ext_vector_type(8)));
typedef _Float16 h4 __attribute__((ext_vector_type(4)));
typedef float f4 __attribute__((ext_vector_type(4)));

#define BDIM 2
#define TDIM 2048
#define DDIM 2048
#define NQ 8
#define NKV 4
#define HDIM 256
#define FDIM 8192
#define MROWS (BDIM * TDIM)   // 4096
#define WINDOW 1024
#define QS 4096               // combined qkv row stride

#define BAR() asm volatile("s_barrier" ::: "memory")

// gelu(x) = x * sigmoid(1.59577*(x + 0.044715 x^3)) (tanh form, exp-based)
__device__ __forceinline__ float gelu_fast(float x) {
  float u = 1.5957691216057308f * (x + 0.044715f * x * x * x);
  float e = __expf(u);
  return x * e / (e + 1.f);
}

// async global->LDS, 16B per lane; LDS dest is wave-uniform base + lane*16
__device__ __forceinline__ void g2l16(const _Float16* g, _Float16* l) {
  __builtin_amdgcn_global_load_lds(
      (const __attribute__((address_space(1))) void*)g,
      (__attribute__((address_space(3))) void*)l, 16, 0, 0);
}

__device__ inline float block_sum(float v, float* sbuf) {
#pragma unroll
  for (int off = 32; off; off >>= 1) v += __shfl_xor(v, off, 64);
  __syncthreads();
  if ((threadIdx.x & 63) == 0) sbuf[threadIdx.x >> 6] = v;
  __syncthreads();
  return sbuf[0] + sbuf[1] + sbuf[2] + sbuf[3];
}

// ---------------------------------------------------------------------------
// GEMM: C[M,Nc] = A[M,K](fp16) * Bt[Nc,K]^T (fp16).  (unchanged from R5)
// 256x128 block tile, BK=64, 512 threads (8 waves, 4M x 2N, 64x64/wave).
// 3 LDS tile-buffers (144KB), counted vmcnt(6), XOR chunk-swizzle staged
// via pre-swizzled global source, N-fastest XCD chunk (A-panel L2-resident).
// EPI: 0 = f32 store, 1 = fp16 store.
template <int EPI>
__global__ __launch_bounds__(512, 2) void gemm256(
    const _Float16* __restrict__ A, const _Float16* __restrict__ Bt,
    void* __restrict__ Cout, int M, int Nc, int K) {
  __shared__ _Float16 As[3][256 * 64];   // 96KB
  __shared__ _Float16 Bs[3][128 * 64];   // 48KB
  (void)M;
  const int tid = threadIdx.x;
  const int lane = tid & 63, w = tid >> 6;
  const int nwg = gridDim.x;
  const int bid2 = (blockIdx.x & 7) * (nwg >> 3) + (blockIdx.x >> 3);
  const int nbx = Nc >> 7;
  const int bx = bid2 % nbx, by = bid2 / nbx;
  const int m0 = by * 256, n0 = bx * 128;
  const int wm = (w >> 1) * 64, wn = (w & 1) * 64;
  const int l16 = lane & 15, quad = lane >> 4;

  const int lr = lane >> 3;                        // row within 8-row group
  const int swz8 = ((lane & 7) ^ lr) << 3;         // swizzled col (halves)
  const _Float16* Ag = A + (size_t)(m0 + w * 32 + lr) * K + swz8;
  const _Float16* Bg = Bt + (size_t)(n0 + w * 16 + lr) * K + swz8;

  const int qs8 = (quad ^ (l16 & 3)) << 3;
  const int kxo = ((l16 >> 2) & 1) << 5;
  int aoff[4], boff[4];
#pragma unroll
  for (int i = 0; i < 4; i++) {
    aoff[i] = (wm + i * 16 + l16) * 64 + qs8;
    boff[i] = (wn + i * 16 + l16) * 64 + qs8;
  }

  f4 acc[4][4];
#pragma unroll
  for (int i = 0; i < 4; i++)
#pragma unroll
    for (int j = 0; j < 4; j++) {
      acc[i][j][0] = 0.f; acc[i][j][1] = 0.f; acc[i][j][2] = 0.f; acc[i][j][3] = 0.f;
    }

#define SA(b, kt, c) g2l16(Ag + (size_t)(c) * 8 * K + (size_t)(kt) * 64, \
                           &As[b][(w * 32 + (c) * 8) * 64])
#define SB(b, kt, c) g2l16(Bg + (size_t)(c) * 8 * K + (size_t)(kt) * 64, \
                           &Bs[b][(w * 16 + (c) * 8) * 64])

  SA(0, 0, 0); SA(0, 0, 1); SA(0, 0, 2); SA(0, 0, 3); SB(0, 0, 0); SB(0, 0, 1);
  SA(1, 1, 0); SA(1, 1, 1); SA(1, 1, 2); SA(1, 1, 3); SB(1, 1, 0); SB(1, 1, 1);
  asm volatile("s_waitcnt vmcnt(6)" ::: "memory");
  BAR();

  const int nt = K >> 6;
  for (int kt = 0; kt < nt; ++kt) {
    const int cur = kt % 3, nb = (kt + 2) % 3;
    const bool pf = (kt + 2) < nt;
    const _Float16* Ab = As[cur];
    const _Float16* Bb = Bs[cur];
    h8 af[4][2], bf[4][2];
    // ---- phase 1: mi0-3 x ni0-1 ----
#pragma unroll
    for (int i = 0; i < 4; i++) {
      af[i][0] = *(const h8*)&Ab[aoff[i] + kxo];
      af[i][1] = *(const h8*)&Ab[aoff[i] + (kxo ^ 32)];
    }
#pragma unroll
    for (int i = 0; i < 2; i++) {
      bf[i][0] = *(const h8*)&Bb[boff[i] + kxo];
      bf[i][1] = *(const h8*)&Bb[boff[i] + (kxo ^ 32)];
    }
    if (pf) { SA(nb, kt + 2, 0); SA(nb, kt + 2, 1); SA(nb, kt + 2, 2); }
    BAR();
    __builtin_amdgcn_s_setprio(1);
#pragma unroll
    for (int mi = 0; mi < 4; mi++)
#pragma unroll
      for (int ni = 0; ni < 2; ni++)
#pragma unroll
        for (int ks = 0; ks < 2; ks++)
          acc[mi][ni] = __builtin_amdgcn_mfma_f32_16x16x32_f16(
              af[mi][ks], bf[ni][ks], acc[mi][ni], 0, 0, 0);
    __builtin_amdgcn_s_setprio(0);
    BAR();
    // ---- phase 2: mi0-3 x ni2-3 ----
#pragma unroll
    for (int i = 2; i < 4; i++) {
      bf[i][0] = *(const h8*)&Bb[boff[i] + kxo];
      bf[i][1] = *(const h8*)&Bb[boff[i] + (kxo ^ 32)];
    }
    if (pf) { SA(nb, kt + 2, 3); SB(nb, kt + 2, 0); SB(nb, kt + 2, 1); }
    BAR();
    __builtin_amdgcn_s_setprio(1);
#pragma unroll
    for (int mi = 0; mi < 4; mi++)
#pragma unroll
      for (int ni = 2; ni < 4; ni++)
#pragma unroll
        for (int ks = 0; ks < 2; ks++)
          acc[mi][ni] = __builtin_amdgcn_mfma_f32_16x16x32_f16(
              af[mi][ks], bf[ni][ks], acc[mi][ni], 0, 0, 0);
    __builtin_amdgcn_s_setprio(0);
    if (pf)                 asm volatile("s_waitcnt vmcnt(6)" ::: "memory");
    else if (kt + 2 == nt)  asm volatile("s_waitcnt vmcnt(0)" ::: "memory");
    BAR();
  }
#undef SA
#undef SB

#pragma unroll
  for (int mi = 0; mi < 4; mi++)
#pragma unroll
    for (int ni = 0; ni < 4; ni++)
#pragma unroll
      for (int r = 0; r < 4; r++) {
        const int rg = m0 + wm + mi * 16 + quad * 4 + r;
        const int cg = n0 + wn + ni * 16 + l16;
        const size_t idx = (size_t)rg * Nc + cg;
        if (EPI == 0) ((float*)Cout)[idx] = acc[mi][ni][r];
        else          ((_Float16*)Cout)[idx] = (_Float16)acc[mi][ni][r];
      }
}

// ---------------------------------------------------------------------------
// dual-B gating GEMM R6: act = gelu(A*B0^T) * (A*B1^T), fp16 out.
// 256x128 block tile, BK=64, 8 waves (4M x 2N, 64x64/wave, dual acc).
// Double-buffered (128KB LDS). Stage for tile kt+1 issued at TOP of iter kt
// (full-iteration slack), single vmcnt(0) per iter. M-fastest XCD chunk:
// B0+B1 panel pair (1MB) L2-resident across its 16-block group -> B traffic
// compulsory-only; A panels stream from LLC (16MB, LLC-resident).
__global__ __launch_bounds__(512, 2) void gemm_gate256(
    const _Float16* __restrict__ A, const _Float16* __restrict__ B0,
    const _Float16* __restrict__ B1, _Float16* __restrict__ act,
    int M, int Nc, int K) {
  __shared__ _Float16 As[2][256 * 64];    // 64KB
  __shared__ _Float16 B0s[2][128 * 64];   // 32KB
  __shared__ _Float16 B1s[2][128 * 64];   // 32KB
  const int tid = threadIdx.x;
  const int lane = tid & 63, w = tid >> 6;
  const int nwg = gridDim.x;
  const int bid2 = (blockIdx.x & 7) * (nwg >> 3) + (blockIdx.x >> 3);
  const int nby = M >> 8;                  // M-fastest within chunk
  const int by = bid2 % nby, bx = bid2 / nby;
  const int m0 = by * 256, n0 = bx * 128;
  const int wm = (w >> 1) * 64, wn = (w & 1) * 64;
  const int l16 = lane & 15, quad = lane >> 4;

  const int lr = lane >> 3;
  const int swz8 = ((lane & 7) ^ lr) << 3;
  const _Float16* Ag  = A  + (size_t)(m0 + w * 32 + lr) * K + swz8;
  const _Float16* B0g = B0 + (size_t)(n0 + w * 16 + lr) * K + swz8;
  const _Float16* B1g = B1 + (size_t)(n0 + w * 16 + lr) * K + swz8;

  const int qs8 = (quad ^ (l16 & 3)) << 3;
  const int kxo = ((l16 >> 2) & 1) << 5;
  int aoff[4], boff[4];
#pragma unroll
  for (int i = 0; i < 4; i++) {
    aoff[i] = (wm + i * 16 + l16) * 64 + qs8;
    boff[i] = (wn + i * 16 + l16) * 64 + qs8;
  }

  f4 acc0[4][4], acc1[4][4];
#pragma unroll
  for (int i = 0; i < 4; i++)
#pragma unroll
    for (int j = 0; j < 4; j++) {
      acc0[i][j][0] = 0.f; acc0[i][j][1] = 0.f; acc0[i][j][2] = 0.f; acc0[i][j][3] = 0.f;
      acc1[i][j][0] = 0.f; acc1[i][j][1] = 0.f; acc1[i][j][2] = 0.f; acc1[i][j][3] = 0.f;
    }

#define SA(b, kt, c)  g2l16(Ag  + (size_t)(c) * 8 * K + (size_t)(kt) * 64, \
                            &As[b][(w * 32 + (c) * 8) * 64])
#define SB0(b, kt, c) g2l16(B0g + (size_t)(c) * 8 * K + (size_t)(kt) * 64, \
                            &B0s[b][(w * 16 + (c) * 8) * 64])
#define SB1(b, kt, c) g2l16(B1g + (size_t)(c) * 8 * K + (size_t)(kt) * 64, \
                            &B1s[b][(w * 16 + (c) * 8) * 64])

  // prologue: stage tile 0 into buf0, drain, barrier
  SA(0, 0, 0); SA(0, 0, 1); SA(0, 0, 2); SA(0, 0, 3);
  SB0(0, 0, 0); SB0(0, 0, 1); SB1(0, 0, 0); SB1(0, 0, 1);
  asm volatile("s_waitcnt vmcnt(0)" ::: "memory");
  BAR();

  const int nt = K >> 6;
  for (int kt = 0; kt < nt; ++kt) {
    const int cur = kt & 1, nb = cur ^ 1;
    const bool pf = (kt + 1) < nt;
    const _Float16* Ab  = As[cur];
    const _Float16* Bb0 = B0s[cur];
    const _Float16* Bb1 = B1s[cur];
    h8 af[4][2], b0f[4][2], b1f[4][2];
    // ---- phase A: acc0 (gate half) + stage ALL of tile kt+1 ----
#pragma unroll
    for (int i = 0; i < 4; i++) {
      af[i][0] = *(const h8*)&Ab[aoff[i] + kxo];
      af[i][1] = *(const h8*)&Ab[aoff[i] + (kxo ^ 32)];
    }
#pragma unroll
    for (int i = 0; i < 4; i++) {
      b0f[i][0] = *(const h8*)&Bb0[boff[i] + kxo];
      b0f[i][1] = *(const h8*)&Bb0[boff[i] + (kxo ^ 32)];
    }
    if (pf) {
      SA(nb, kt + 1, 0); SA(nb, kt + 1, 1); SA(nb, kt + 1, 2); SA(nb, kt + 1, 3);
      SB0(nb, kt + 1, 0); SB0(nb, kt + 1, 1);
      SB1(nb, kt + 1, 0); SB1(nb, kt + 1, 1);
    }
    BAR();
    __builtin_amdgcn_s_setprio(1);
#pragma unroll
    for (int mi = 0; mi < 4; mi++)
#pragma unroll
      for (int ni = 0; ni < 4; ni++)
#pragma unroll
        for (int ks = 0; ks < 2; ks++)
          acc0[mi][ni] = __builtin_amdgcn_mfma_f32_16x16x32_f16(
              af[mi][ks], b0f[ni][ks], acc0[mi][ni], 0, 0, 0);
    __builtin_amdgcn_s_setprio(0);
    BAR();
    // ---- phase B: acc1 (mult half) ----
#pragma unroll
    for (int i = 0; i < 4; i++) {
      b1f[i][0] = *(const h8*)&Bb1[boff[i] + kxo];
      b1f[i][1] = *(const h8*)&Bb1[boff[i] + (kxo ^ 32)];
    }
    BAR();
    __builtin_amdgcn_s_setprio(1);
#pragma unroll
    for (int mi = 0; mi < 4; mi++)
#pragma unroll
      for (int ni = 0; ni < 4; ni++)
#pragma unroll
        for (int ks = 0; ks < 2; ks++)
          acc1[mi][ni] = __builtin_amdgcn_mfma_f32_16x16x32_f16(
              af[mi][ks], b1f[ni][ks], acc1[mi][ni], 0, 0, 0);
    __builtin_amdgcn_s_setprio(0);
    if (pf) asm volatile("s_waitcnt vmcnt(0)" ::: "memory");
    BAR();
  }
#undef SA
#undef SB0
#undef SB1

#pragma unroll
  for (int mi = 0; mi < 4; mi++)
#pragma unroll
    for (int ni = 0; ni < 4; ni++)
#pragma unroll
      for (int r = 0; r < 4; r++) {
        const int rg = m0 + wm + mi * 16 + quad * 4 + r;
        const int cg = n0 + wn + ni * 16 + l16;
        act[(size_t)rg * Nc + cg] =
            (_Float16)(gelu_fast(acc0[mi][ni][r]) * acc1[mi][ni][r]);
      }
}

// ------------- transpose + cast f32 [R,C] -> fp16 [C,R], per-z slab --------
__global__ __launch_bounds__(256) void transpose_cast_kernel(
    const float* __restrict__ in, _Float16* __restrict__ out,
    int R, int C, size_t in_zstride, size_t out_zstride) {
  __shared__ float tile[64][65];
  const float* ip = in + blockIdx.z * in_zstride;
  _Float16* op = out + blockIdx.z * out_zstride;
  const int cb = blockIdx.x * 64, rb = blockIdx.y * 64;
  const int tx = threadIdx.x & 15, ty = threadIdx.x >> 4;
#pragma unroll
  for (int i = 0; i < 4; i++) {
    f4 v = *(const f4*)&ip[(size_t)(rb + ty + 16 * i) * C + cb + tx * 4];
    tile[ty + 16 * i][tx * 4 + 0] = v[0];
    tile[ty + 16 * i][tx * 4 + 1] = v[1];
    tile[ty + 16 * i][tx * 4 + 2] = v[2];
    tile[ty + 16 * i][tx * 4 + 3] = v[3];
  }
  __syncthreads();
#pragma unroll
  for (int i = 0; i < 4; i++) {
    const int c = ty + 16 * i;
    h4 o;
#pragma unroll
    for (int j = 0; j < 4; j++) o[j] = (_Float16)tile[tx * 4 + j][c];
    *(h4*)&op[(size_t)(cb + c) * R + rb + tx * 4] = o;
  }
}

// ----------------------------- f32 -> fp16 cast ----------------------------
__global__ void cast_fp16_kernel(const float* __restrict__ in,
                                 _Float16* __restrict__ out, int n4) {
  int i = blockIdx.x * 256 + threadIdx.x;
  if (i < n4) {
    f4 v = ((const f4*)in)[i];
    h4 o;
    o[0] = (_Float16)v[0]; o[1] = (_Float16)v[1];
    o[2] = (_Float16)v[2]; o[3] = (_Float16)v[3];
    ((h4*)out)[i] = o;
  }
}

// -------------------- RMS-norm over 2048-row -> fp16 out -------------------
__global__ __launch_bounds__(256) void rmsnorm_fp16_kernel(
    const float* __restrict__ in, const float* __restrict__ scale,
    _Float16* __restrict__ out) {
  __shared__ float sbuf[4];
  const int row = blockIdx.x, tid = threadIdx.x;
  const float* r = in + (size_t)row * 2048;
  f4 a = ((const f4*)r)[tid];
  f4 b = ((const f4*)r)[tid + 256];
  float ss = a[0]*a[0] + a[1]*a[1] + a[2]*a[2] + a[3]*a[3] +
             b[0]*b[0] + b[1]*b[1] + b[2]*b[2] + b[3]*b[3];
  float tot = block_sum(ss, sbuf);
  float rs = rsqrtf(tot * (1.f / 2048.f) + 1e-6f);
  f4 s0 = ((const f4*)scale)[tid];
  f4 s1 = ((const f4*)scale)[tid + 256];
  h4 o0, o1;
#pragma unroll
  for (int j = 0; j < 4; j++) {
    o0[j] = (_Float16)(a[j] * rs * (1.f + s0[j]));
    o1[j] = (_Float16)(b[j] * rs * (1.f + s1[j]));
  }
  ((h4*)(out + (size_t)row * 2048))[tid] = o0;
  ((h4*)(out + (size_t)row * 2048))[tid + 256] = o1;
}

// --- fused per-head norm/RoPE over combined qkv rows (fp16 in, fp16 out) ---
__global__ __launch_bounds__(256) void headnorm_qkv_kernel(
    const _Float16* __restrict__ qkv, _Float16* __restrict__ out,
    const float* __restrict__ qsc, const float* __restrict__ ksc,
    const int* __restrict__ pos_arr) {
  const int inst = blockIdx.x * 4 + (threadIdx.x >> 6);
  const int lane = threadIdx.x & 63;
  const int row = inst >> 4, slot = inst & 15;
  const _Float16* r = qkv + (size_t)row * QS + slot * 256;
  h4 vh = ((const h4*)r)[lane];
  f4 v;
#pragma unroll
  for (int j = 0; j < 4; j++) v[j] = (float)vh[j];
  float ss = v[0]*v[0] + v[1]*v[1] + v[2]*v[2] + v[3]*v[3];
#pragma unroll
  for (int off = 32; off; off >>= 1) ss += __shfl_xor(ss, off, 64);
  const float rs = rsqrtf(ss * (1.f / 256.f) + 1e-6f);
  const float* scale = (slot < 8) ? qsc : (slot < 12 ? ksc : nullptr);
  f4 nv;
  if (scale) {
    f4 sc = ((const f4*)scale)[lane];
#pragma unroll
    for (int j = 0; j < 4; j++) nv[j] = v[j] * rs * (1.f + sc[j]);
  } else {
#pragma unroll
    for (int j = 0; j < 4; j++) nv[j] = v[j] * rs;
  }
  h4 res;
  if (slot < 12) {  // rope for q and k
    const float pos = (float)pos_arr[row];
    const bool lo = lane < 32;
#pragma unroll
    for (int j = 0; j < 4; j++) {
      float partner = __shfl_xor(nv[j], 32, 64);
      const int ph = (lane * 4 + j) & 127;
      float it = exp2f((float)ph * -0.103810253f);  // 10000^(-p/128)
      float ang = pos * it;
      float sn, cs;
      sincosf(ang, &sn, &cs);
      res[j] = (_Float16)(lo ? (nv[j] * cs - partner * sn)
                             : (nv[j] * cs + partner * sn));
    }
  } else {
#pragma unroll
    for (int j = 0; j < 4; j++) res[j] = (_Float16)nv[j];
  }
  ((h4*)(out + (size_t)row * QS + slot * 256))[lane] = res;
}

// ---- transpose V slots of qkvh: [row][3072+kvh*256+h] -> vT[b,kvh,h,t] ----
__global__ __launch_bounds__(256) void transpose_v_kernel(
    const _Float16* __restrict__ qkvh, _Float16* __restrict__ vT) {
  __shared__ _Float16 tile[32][33];
  const int z = blockIdx.z;
  const int b = z >> 2, kvh = z & 3;
  const int tb = blockIdx.x * 32, hb = blockIdx.y * 32;
  const int x = threadIdx.x, y = threadIdx.y;
#pragma unroll
  for (int i = 0; i < 4; i++)
    tile[y + 8 * i][x] =
        qkvh[(size_t)(b * TDIM + tb + y + 8 * i) * QS + 3072 + kvh * 256 + hb + x];
  __syncthreads();
#pragma unroll
  for (int i = 0; i < 4; i++)
    vT[((size_t)z * HDIM + hb + y + 8 * i) * TDIM + tb + x] = tile[x][y + 8 * i];
}

// --------------------- flash attention, 64 q-rows / block ------------------
// Ks [32][256]h and Vs [256][32]h XOR-chunk-swizzled (R5-verified).
__global__ __launch_bounds__(256) void attn_kernel(
    const _Float16* __restrict__ qkvh, const _Float16* __restrict__ vT,
    _Float16* __restrict__ enc) {
  __shared__ _Float16 Ks[32 * 256];
  __shared__ _Float16 Vs[256 * 32];
  __shared__ _Float16 Ps[4][16 * 32];
  const int t0 = blockIdx.x * 64;
  const int n = blockIdx.y;
  const int b = blockIdx.z;
  const int kvh = n >> 1;
  const int tid = threadIdx.x;
  const int w = tid >> 6, lane = tid & 63, l16 = lane & 15, quad = lane >> 4;
  const int kxr = (l16 >> 2) & 1;                  // Ks ks-plane phys xor
  const int qsK8 = (quad ^ (l16 & 3)) << 3;        // Ks chunk swizzle (halves)
  const int qsV8 = (quad ^ ((l16 >> 1) & 3)) << 3; // Vs chunk swizzle (halves)

  h8 qfrag[8];
  {
    const int trow = t0 + w * 16 + l16;
    const _Float16* qp =
        qkvh + (size_t)(b * TDIM + trow) * QS + n * HDIM + quad * 8;
#pragma unroll
    for (int ks = 0; ks < 8; ks++) qfrag[ks] = *(const h8*)(qp + ks * 32);
  }

  f4 O[16];
#pragma unroll
  for (int i = 0; i < 16; i++) { O[i][0] = 0.f; O[i][1] = 0.f; O[i][2] = 0.f; O[i][3] = 0.f; }
  float m_i[4], l_i[4];
#pragma unroll
  for (int r = 0; r < 4; r++) { m_i[r] = -1e30f; l_i[r] = 0.f; }

  int s_begin = t0 - (WINDOW - 1);
  if (s_begin < 0) s_begin = 0;
  s_begin &= ~31;
  const int s_end = t0 + 64;
  const _Float16* kbase = qkvh + (size_t)b * TDIM * QS + 2048 + kvh * HDIM;
  const _Float16* vbase = vT + ((size_t)(b * NKV + kvh) * HDIM) * TDIM;

  for (int s0 = s_begin; s0 < s_end; s0 += 32) {
    __syncthreads();
#pragma unroll
    for (int p = 0; p < 4; p++) {
      int g = p * 256 + tid;
      {
        int si = g >> 5, c = g & 31;
        *(h8*)&Ks[si * 256 + ((c ^ (si & 7)) << 3)] =
            *(const h8*)(kbase + (size_t)(s0 + si) * QS + (c << 3));
      }
      {
        int h = g >> 2, c = g & 3;
        *(h8*)&Vs[h * 32 + ((c ^ ((g >> 3) & 3)) << 3)] =
            *(const h8*)(vbase + (size_t)h * TDIM + s0 + (c << 3));
      }
    }
    __syncthreads();

    float P[2][4], cmax[4];
#pragma unroll
    for (int r = 0; r < 4; r++) cmax[r] = -1e30f;
#pragma unroll
    for (int sc = 0; sc < 2; sc++) {
      f4 lg; lg[0] = 0.f; lg[1] = 0.f; lg[2] = 0.f; lg[3] = 0.f;
#pragma unroll
      for (int ks = 0; ks < 8; ks++) {
        h8 kb = *(const h8*)&Ks[(sc * 16 + l16) * 256 + ((ks ^ kxr) << 5) + qsK8];
        lg = __builtin_amdgcn_mfma_f32_16x16x32_f16(qfrag[ks], kb, lg, 0, 0, 0);
      }
      const int scol = s0 + sc * 16 + l16;
#pragma unroll
      for (int r = 0; r < 4; r++) {
        const int trow = t0 + w * 16 + quad * 4 + r;
        // 50*tanh(lg/50): tanh(y)=(e^2y-1)/(e^2y+1), e^2y = expf(lg*0.04)
        float t = __expf(lg[r] * 0.04f);
        float xv = 50.f - 100.f * __builtin_amdgcn_rcpf(t + 1.f);
        bool valid = (scol <= trow) && (scol > trow - WINDOW);
        P[sc][r] = valid ? xv : -1e30f;
        cmax[r] = fmaxf(cmax[r], P[sc][r]);
      }
    }
#pragma unroll
    for (int off = 1; off < 16; off <<= 1)
#pragma unroll
      for (int r = 0; r < 4; r++) cmax[r] = fmaxf(cmax[r], __shfl_xor(cmax[r], off, 16));
    float alpha[4], psum[4];
#pragma unroll
    for (int r = 0; r < 4; r++) {
      float mnew = fmaxf(m_i[r], cmax[r]);
      alpha[r] = __expf(m_i[r] - mnew);
      m_i[r] = mnew;
      psum[r] = 0.f;
    }
#pragma unroll
    for (int sc = 0; sc < 2; sc++)
#pragma unroll
      for (int r = 0; r < 4; r++) {
        float pv = __expf(P[sc][r] - m_i[r]);
        P[sc][r] = pv;
        psum[r] += pv;
      }
#pragma unroll
    for (int off = 1; off < 16; off <<= 1)
#pragma unroll
      for (int r = 0; r < 4; r++) psum[r] += __shfl_xor(psum[r], off, 16);
#pragma unroll
    for (int r = 0; r < 4; r++) l_i[r] = l_i[r] * alpha[r] + psum[r];
#pragma unroll
    for (int i = 0; i < 16; i++)
#pragma unroll
      for (int r = 0; r < 4; r++) O[i][r] *= alpha[r];
#pragma unroll
    for (int sc = 0; sc < 2; sc++)
#pragma unroll
      for (int r = 0; r < 4; r++)
        Ps[w][(quad * 4 + r) * 32 + sc * 16 + l16] = (_Float16)P[sc][r];
    h8 pa = *(const h8*)&Ps[w][l16 * 32 + quad * 8];
#pragma unroll
    for (int ht = 0; ht < 16; ht++) {
      h8 vb = *(const h8*)&Vs[(ht * 16 + l16) * 32 + qsV8];
      O[ht] = __builtin_amdgcn_mfma_f32_16x16x32_f16(pa, vb, O[ht], 0, 0, 0);
    }
  }

  float invl[4];
#pragma unroll
  for (int r = 0; r < 4; r++) invl[r] = 1.f / l_i[r];
#pragma unroll
  for (int ht = 0; ht < 16; ht++)
#pragma unroll
    for (int r = 0; r < 4; r++) {
      const int trow = t0 + w * 16 + quad * 4 + r;
      enc[((size_t)(b * TDIM + trow)) * (NQ * HDIM) + n * HDIM + ht * 16 + l16] =
          (_Float16)(O[ht][r] * invl[r]);
    }
}

// ------ post-attn: residual + norm, then pre-FFW norm (fused) --------------
__global__ __launch_bounds__(256) void postattn_kernel(
    const float* __restrict__ attnraw, const float* __restrict__ x,
    const float* __restrict__ post_scale, const float* __restrict__ pre_ffw_scale,
    const float* __restrict__ skip, float* __restrict__ attn_out,
    _Float16* __restrict__ ffw_in) {
  __shared__ float sbuf[4];
  const int row = blockIdx.x, tid = threadIdx.x;
  const float* ar = attnraw + (size_t)row * 2048;
  const float* xr = x + (size_t)row * 2048;
  f4 a0 = ((const f4*)ar)[tid], a1 = ((const f4*)ar)[tid + 256];
  float ss = a0[0]*a0[0] + a0[1]*a0[1] + a0[2]*a0[2] + a0[3]*a0[3] +
             a1[0]*a1[0] + a1[1]*a1[1] + a1[2]*a1[2] + a1[3]*a1[3];
  float tot = block_sum(ss, sbuf);
  float rs = rsqrtf(tot * (1.f / 2048.f) + 1e-6f);
  const float sk = skip[0];
  f4 x0 = ((const f4*)xr)[tid], x1 = ((const f4*)xr)[tid + 256];
  f4 p0 = ((const f4*)post_scale)[tid], p1 = ((const f4*)post_scale)[tid + 256];
  f4 at0, at1;
#pragma unroll
  for (int j = 0; j < 4; j++) {
    at0[j] = x0[j] * sk + a0[j] * rs * (1.f + p0[j]);
    at1[j] = x1[j] * sk + a1[j] * rs * (1.f + p1[j]);
  }
  ((f4*)(attn_out + (size_t)row * 2048))[tid] = at0;
  ((f4*)(attn_out + (size_t)row * 2048))[tid + 256] = at1;
  float ss2 = at0[0]*at0[0] + at0[1]*at0[1] + at0[2]*at0[2] + at0[3]*at0[3] +
              at1[0]*at1[0] + at1[1]*at1[1] + at1[2]*at1[2] + at1[3]*at1[3];
  float tot2 = block_sum(ss2, sbuf);
  float rs2 = rsqrtf(tot2 * (1.f / 2048.f) + 1e-6f);
  f4 f0 = ((const f4*)pre_ffw_scale)[tid], f1 = ((const f4*)pre_ffw_scale)[tid + 256];
  h4 o0, o1;
#pragma unroll
  for (int j = 0; j < 4; j++) {
    o0[j] = (_Float16)(at0[j] * rs2 * (1.f + f0[j]));
    o1[j] = (_Float16)(at1[j] * rs2 * (1.f + f1[j]));
  }
  ((h4*)(ffw_in + (size_t)row * 2048))[tid] = o0;
  ((h4*)(ffw_in + (size_t)row * 2048))[tid + 256] = o1;
}

// ------ final: out = attn_out + rmsnorm(ffw_fp16, post_ffw_scale) ----------
__global__ __launch_bounds__(256) void final_kernel(
    const _Float16* __restrict__ ffw, const float* __restrict__ attn_out,
    const float* __restrict__ post_ffw_scale, float* __restrict__ out) {
  __shared__ float sbuf[4];
  const int row = blockIdx.x, tid = threadIdx.x;
  const _Float16* fr = ffw + (size_t)row * 2048;
  const float* ar = attn_out + (size_t)row * 2048;
  h4 fh0 = ((const h4*)fr)[tid], fh1 = ((const h4*)fr)[tid + 256];
  f4 a0, a1;
#pragma unroll
  for (int j = 0; j < 4; j++) { a0[j] = (float)fh0[j]; a1[j] = (float)fh1[j]; }
  float ss = a0[0]*a0[0] + a0[1]*a0[1] + a0[2]*a0[2] + a0[3]*a0[3] +
             a1[0]*a1[0] + a1[1]*a1[1] + a1[2]*a1[2] + a1[3]*a1[3];
  float tot = block_sum(ss, sbuf);
  float rs = rsqrtf(tot * (1.f / 2048.f) + 1e-6f);
  f4 s0 = ((const f4*)post_ffw_scale)[tid], s1 = ((const f4*)post_ffw_scale)[tid + 256];
  f4 x0 = ((const f4*)ar)[tid], x1 = ((const f4*)ar)[tid + 256];
  f4 o0, o1;
#pragma unroll
  for (int j = 0; j < 4; j++) {
    o0[j] = x0[j] + a0[j] * rs * (1.f + s0[j]);
    o1[j] = x1[j] + a1[j] * rs * (1.f + s1[j]);
  }
  ((f4*)(out + (size_t)row * 2048))[tid] = o0;
  ((f4*)(out + (size_t)row * 2048))[tid + 256] = o1;
}

// ---------------------------------------------------------------------------
extern "C" void kernel_launch(void* const* d_in, const int* in_sizes, int n_in,
                              void* d_out, int out_size, void* d_ws, size_t ws_size,
                              hipStream_t stream) {
  (void)in_sizes; (void)n_in; (void)out_size; (void)ws_size;
  const float* x              = (const float*)d_in[0];
  const int*   segment_pos    = (const int*)d_in[1];
  const float* w_q            = (const float*)d_in[7];
  const float* w_kv           = (const float*)d_in[8];
  const float* w_attn_vec     = (const float*)d_in[9];
  const float* q_norm_scale   = (const float*)d_in[10];
  const float* k_norm_scale   = (const float*)d_in[11];
  const float* pre_attn_scale = (const float*)d_in[12];
  const float* post_attn_scale= (const float*)d_in[13];
  const float* pre_ffw_scale  = (const float*)d_in[14];
  const float* post_ffw_scale = (const float*)d_in[15];
  const float* w_gating       = (const float*)d_in[16];
  const float* w_linear       = (const float*)d_in[17];
  const float* skip_scale     = (const float*)d_in[18];

  char* ws = (char*)d_ws;
  const size_t MB = 1024 * 1024;
  // weight arena [0,64MB): Wqkv (16MB) -> Wo (8MB) -> Wg (64MB) -> Wl (32MB)
  _Float16* Wqkv  = (_Float16*)(ws + 0);
  _Float16* Wo    = (_Float16*)(ws + 0);
  _Float16* Wg    = (_Float16*)(ws + 0);
  _Float16* Wl    = (_Float16*)(ws + 0);
  _Float16* Hbf   = (_Float16*)(ws + 64 * MB);   // 16MB: h, later ffw_in
  float* attnF    = (float*)(ws + 80 * MB);      // 32MB residual
  _Float16* qkvraw= (_Float16*)(ws + 112 * MB);  // 32MB [4096][4096] fp16
  _Float16* qkvh  = (_Float16*)(ws + 144 * MB);  // 32MB
  _Float16* enc   = (_Float16*)(ws + 176 * MB);  // 16MB
  float* attnraw  = (float*)(ws + 192 * MB);     // 32MB
  _Float16* vT    = (_Float16*)(ws + 224 * MB);  //  8MB
  _Float16* act   = (_Float16*)(ws + 112 * MB);  // 64MB (qkvraw/qkvh dead)
  _Float16* ffw   = (_Float16*)(ws + 192 * MB);  // 16MB (attnraw dead)
  float* outp     = (float*)d_out;

  // --- weight prep: per-head [D,H]->[H,D], stacked q|k|v into Wqkv ---
  transpose_cast_kernel<<<dim3(HDIM / 64, DDIM / 64, NQ), 256, 0, stream>>>(
      w_q, Wqkv, DDIM, HDIM, (size_t)DDIM * HDIM, (size_t)HDIM * DDIM);
  transpose_cast_kernel<<<dim3(HDIM / 64, DDIM / 64, NKV), 256, 0, stream>>>(
      w_kv, Wqkv + (size_t)2048 * DDIM, DDIM, HDIM,
      (size_t)DDIM * HDIM, (size_t)HDIM * DDIM);
  transpose_cast_kernel<<<dim3(HDIM / 64, DDIM / 64, NKV), 256, 0, stream>>>(
      w_kv + (size_t)NKV * DDIM * HDIM, Wqkv + (size_t)3072 * DDIM, DDIM, HDIM,
      (size_t)DDIM * HDIM, (size_t)HDIM * DDIM);
  // --- h = rmsnorm(x, pre_attn_scale) ---
  rmsnorm_fp16_kernel<<<MROWS, 256, 0, stream>>>(x, pre_attn_scale, Hbf);
  // --- fused QKV projection (fp16 out): 512 wgs ---
  gemm256<1><<<dim3((QS / 128) * (MROWS / 256)), 512, 0, stream>>>(
      Hbf, Wqkv, qkvraw, MROWS, QS, DDIM);
  // --- fused per-head norms + RoPE over all 16 head-slots ---
  headnorm_qkv_kernel<<<(MROWS * 16) / 4, 256, 0, stream>>>(
      qkvraw, qkvh, q_norm_scale, k_norm_scale, segment_pos);
  transpose_v_kernel<<<dim3(TDIM / 32, HDIM / 32, BDIM * NKV), dim3(32, 8), 0, stream>>>(
      qkvh, vT);
  // --- attention ---
  attn_kernel<<<dim3(TDIM / 64, NQ, BDIM), 256, 0, stream>>>(qkvh, vT, enc);
  // --- output projection: 256 wgs ---
  transpose_cast_kernel<<<dim3(DDIM / 64, (NQ * HDIM) / 64, 1), 256, 0, stream>>>(
      w_attn_vec, Wo, NQ * HDIM, DDIM, 0, 0);
  gemm256<0><<<dim3((DDIM / 128) * (MROWS / 256)), 512, 0, stream>>>(
      enc, Wo, attnraw, MROWS, DDIM, NQ * HDIM);
  // --- post-attn norm + residual, pre-FFW norm ---
  postattn_kernel<<<MROWS, 256, 0, stream>>>(attnraw, x, post_attn_scale,
                                             pre_ffw_scale, skip_scale, attnF, Hbf);
  // --- FFN: fused dual-gating GEMM, 256x128 tile: 1024 wgs ---
  cast_fp16_kernel<<<(2 * FDIM * DDIM / 4 + 255) / 256, 256, 0, stream>>>(
      w_gating, Wg, 2 * FDIM * DDIM / 4);
  gemm_gate256<<<dim3((FDIM / 128) * (MROWS / 256)), 512, 0, stream>>>(
      Hbf, Wg, Wg + (size_t)FDIM * DDIM, act, MROWS, FDIM, DDIM);
  // --- linear (fp16 out): 256 wgs ---
  transpose_cast_kernel<<<dim3(DDIM / 64, FDIM / 64, 1), 256, 0, stream>>>(
      w_linear, Wl, FDIM, DDIM, 0, 0);
  gemm256<1><<<dim3((DDIM / 128) * (MROWS / 256)), 512, 0, stream>>>(
      act, Wl, ffw, MROWS, DDIM, FDIM);
  // --- final norm + residual ---
  final_kernel<<<MROWS, 256, 0, stream>>>(ffw, attnF, post_ffw_scale, outp);
}

// Round 4
// 1086.192 us; speedup vs baseline: 1.0668x; 1.0560x over previous
//
#include <hip/hip_runtime.h>

// ---------------------------------------------------------------------------
// Transformer block (Gemma-style) B=2,T=2048,D=2048,N=8,K=4,H=256,F=8192.
// fp32 in/out, fp16 MFMA internals.
// R7: gate GEMM gets TRUE counted-vmcnt pipelining (T4): mixed-depth LDS —
//     A triple-buffered (96KB, prefetch distance 2: A streams from LLC/HBM,
//     needs ~900cyc-deep slack), B0/B1 double-buffered (64KB: L2-resident,
//     short slack OK). 160KB LDS total (gfx950 WG max; AITER precedent).
//     4 phases x 16 MFMA per K-tile, stages spread 2/phase, end-of-iter
//     s_waitcnt vmcnt(4) (A(kt+2) stays in flight across the barrier;
//     vmcnt(0) only in epilogue). Everything else identical to R6 (passing).
// ---------------------------------------------------------------------------

typedef _Float16 h8 __attribute__((ext_vector_type(8)));
typedef _Float16 h4 __attribute__((ext_vector_type(4)));
typedef float f4 __attribute__((ext_vector_type(4)));

#define BDIM 2
#define TDIM 2048
#define DDIM 2048
#define NQ 8
#define NKV 4
#define HDIM 256
#define FDIM 8192
#define MROWS (BDIM * TDIM)   // 4096
#define WINDOW 1024
#define QS 4096               // combined qkv row stride

#define BAR() asm volatile("s_barrier" ::: "memory")

// gelu(x) = x * sigmoid(1.59577*(x + 0.044715 x^3)) (tanh form, exp-based)
__device__ __forceinline__ float gelu_fast(float x) {
  float u = 1.5957691216057308f * (x + 0.044715f * x * x * x);
  float e = __expf(u);
  return x * e / (e + 1.f);
}

// async global->LDS, 16B per lane; LDS dest is wave-uniform base + lane*16
__device__ __forceinline__ void g2l16(const _Float16* g, _Float16* l) {
  __builtin_amdgcn_global_load_lds(
      (const __attribute__((address_space(1))) void*)g,
      (__attribute__((address_space(3))) void*)l, 16, 0, 0);
}

__device__ inline float block_sum(float v, float* sbuf) {
#pragma unroll
  for (int off = 32; off; off >>= 1) v += __shfl_xor(v, off, 64);
  __syncthreads();
  if ((threadIdx.x & 63) == 0) sbuf[threadIdx.x >> 6] = v;
  __syncthreads();
  return sbuf[0] + sbuf[1] + sbuf[2] + sbuf[3];
}

// ---------------------------------------------------------------------------
// GEMM: C[M,Nc] = A[M,K](fp16) * Bt[Nc,K]^T (fp16).  (unchanged from R5/R6)
// 256x128 block tile, BK=64, 512 threads (8 waves, 4M x 2N, 64x64/wave).
// 3 LDS tile-buffers (144KB), counted vmcnt(6), XOR chunk-swizzle staged
// via pre-swizzled global source, N-fastest XCD chunk.
// EPI: 0 = f32 store, 1 = fp16 store.
template <int EPI>
__global__ __launch_bounds__(512, 2) void gemm256(
    const _Float16* __restrict__ A, const _Float16* __restrict__ Bt,
    void* __restrict__ Cout, int M, int Nc, int K) {
  __shared__ _Float16 As[3][256 * 64];   // 96KB
  __shared__ _Float16 Bs[3][128 * 64];   // 48KB
  (void)M;
  const int tid = threadIdx.x;
  const int lane = tid & 63, w = tid >> 6;
  const int nwg = gridDim.x;
  const int bid2 = (blockIdx.x & 7) * (nwg >> 3) + (blockIdx.x >> 3);
  const int nbx = Nc >> 7;
  const int bx = bid2 % nbx, by = bid2 / nbx;
  const int m0 = by * 256, n0 = bx * 128;
  const int wm = (w >> 1) * 64, wn = (w & 1) * 64;
  const int l16 = lane & 15, quad = lane >> 4;

  const int lr = lane >> 3;                        // row within 8-row group
  const int swz8 = ((lane & 7) ^ lr) << 3;         // swizzled col (halves)
  const _Float16* Ag = A + (size_t)(m0 + w * 32 + lr) * K + swz8;
  const _Float16* Bg = Bt + (size_t)(n0 + w * 16 + lr) * K + swz8;

  const int qs8 = (quad ^ (l16 & 3)) << 3;
  const int kxo = ((l16 >> 2) & 1) << 5;
  int aoff[4], boff[4];
#pragma unroll
  for (int i = 0; i < 4; i++) {
    aoff[i] = (wm + i * 16 + l16) * 64 + qs8;
    boff[i] = (wn + i * 16 + l16) * 64 + qs8;
  }

  f4 acc[4][4];
#pragma unroll
  for (int i = 0; i < 4; i++)
#pragma unroll
    for (int j = 0; j < 4; j++) {
      acc[i][j][0] = 0.f; acc[i][j][1] = 0.f; acc[i][j][2] = 0.f; acc[i][j][3] = 0.f;
    }

#define SA(b, kt, c) g2l16(Ag + (size_t)(c) * 8 * K + (size_t)(kt) * 64, \
                           &As[b][(w * 32 + (c) * 8) * 64])
#define SB(b, kt, c) g2l16(Bg + (size_t)(c) * 8 * K + (size_t)(kt) * 64, \
                           &Bs[b][(w * 16 + (c) * 8) * 64])

  SA(0, 0, 0); SA(0, 0, 1); SA(0, 0, 2); SA(0, 0, 3); SB(0, 0, 0); SB(0, 0, 1);
  SA(1, 1, 0); SA(1, 1, 1); SA(1, 1, 2); SA(1, 1, 3); SB(1, 1, 0); SB(1, 1, 1);
  asm volatile("s_waitcnt vmcnt(6)" ::: "memory");
  BAR();

  const int nt = K >> 6;
  for (int kt = 0; kt < nt; ++kt) {
    const int cur = kt % 3, nb = (kt + 2) % 3;
    const bool pf = (kt + 2) < nt;
    const _Float16* Ab = As[cur];
    const _Float16* Bb = Bs[cur];
    h8 af[4][2], bf[4][2];
    // ---- phase 1: mi0-3 x ni0-1 ----
#pragma unroll
    for (int i = 0; i < 4; i++) {
      af[i][0] = *(const h8*)&Ab[aoff[i] + kxo];
      af[i][1] = *(const h8*)&Ab[aoff[i] + (kxo ^ 32)];
    }
#pragma unroll
    for (int i = 0; i < 2; i++) {
      bf[i][0] = *(const h8*)&Bb[boff[i] + kxo];
      bf[i][1] = *(const h8*)&Bb[boff[i] + (kxo ^ 32)];
    }
    if (pf) { SA(nb, kt + 2, 0); SA(nb, kt + 2, 1); SA(nb, kt + 2, 2); }
    BAR();
    __builtin_amdgcn_s_setprio(1);
#pragma unroll
    for (int mi = 0; mi < 4; mi++)
#pragma unroll
      for (int ni = 0; ni < 2; ni++)
#pragma unroll
        for (int ks = 0; ks < 2; ks++)
          acc[mi][ni] = __builtin_amdgcn_mfma_f32_16x16x32_f16(
              af[mi][ks], bf[ni][ks], acc[mi][ni], 0, 0, 0);
    __builtin_amdgcn_s_setprio(0);
    BAR();
    // ---- phase 2: mi0-3 x ni2-3 ----
#pragma unroll
    for (int i = 2; i < 4; i++) {
      bf[i][0] = *(const h8*)&Bb[boff[i] + kxo];
      bf[i][1] = *(const h8*)&Bb[boff[i] + (kxo ^ 32)];
    }
    if (pf) { SA(nb, kt + 2, 3); SB(nb, kt + 2, 0); SB(nb, kt + 2, 1); }
    BAR();
    __builtin_amdgcn_s_setprio(1);
#pragma unroll
    for (int mi = 0; mi < 4; mi++)
#pragma unroll
      for (int ni = 2; ni < 4; ni++)
#pragma unroll
        for (int ks = 0; ks < 2; ks++)
          acc[mi][ni] = __builtin_amdgcn_mfma_f32_16x16x32_f16(
              af[mi][ks], bf[ni][ks], acc[mi][ni], 0, 0, 0);
    __builtin_amdgcn_s_setprio(0);
    if (pf)                 asm volatile("s_waitcnt vmcnt(6)" ::: "memory");
    else if (kt + 2 == nt)  asm volatile("s_waitcnt vmcnt(0)" ::: "memory");
    BAR();
  }
#undef SA
#undef SB

#pragma unroll
  for (int mi = 0; mi < 4; mi++)
#pragma unroll
    for (int ni = 0; ni < 4; ni++)
#pragma unroll
      for (int r = 0; r < 4; r++) {
        const int rg = m0 + wm + mi * 16 + quad * 4 + r;
        const int cg = n0 + wn + ni * 16 + l16;
        const size_t idx = (size_t)rg * Nc + cg;
        if (EPI == 0) ((float*)Cout)[idx] = acc[mi][ni][r];
        else          ((_Float16*)Cout)[idx] = (_Float16)acc[mi][ni][r];
      }
}

// ---------------------------------------------------------------------------
// dual-B gating GEMM R7: act = gelu(A*B0^T) * (A*B1^T), fp16 out.
// 256x128 block tile, BK=64, 8 waves (4M x 2N, 64x64/wave, dual acc).
// Mixed-depth LDS (160KB): A 3-buf (dist-2 prefetch), B0/B1 2-buf (dist-1,
// L2-resident). 4 phases x 16 MFMA; stages spread: P1 B0(kt+1), P2 B1(kt+1),
// P3/P4 A(kt+2). End-of-iter vmcnt(4): retires through B(kt+1) (and the
// older A(kt+1)); A(kt+2)'s 4 loads stay in flight across the barrier.
// M-fastest XCD chunk ordering (B panel pair L2-resident) kept from R6.
__global__ __launch_bounds__(512, 1) void gemm_gate256(
    const _Float16* __restrict__ A, const _Float16* __restrict__ B0,
    const _Float16* __restrict__ B1, _Float16* __restrict__ act,
    int M, int Nc, int K) {
  __shared__ _Float16 As[3][256 * 64];    // 96KB
  __shared__ _Float16 B0s[2][128 * 64];   // 32KB
  __shared__ _Float16 B1s[2][128 * 64];   // 32KB
  const int tid = threadIdx.x;
  const int lane = tid & 63, w = tid >> 6;
  const int nwg = gridDim.x;
  const int bid2 = (blockIdx.x & 7) * (nwg >> 3) + (blockIdx.x >> 3);
  const int nby = M >> 8;                  // M-fastest within chunk
  const int by = bid2 % nby, bx = bid2 / nby;
  const int m0 = by * 256, n0 = bx * 128;
  const int wm = (w >> 1) * 64, wn = (w & 1) * 64;
  const int l16 = lane & 15, quad = lane >> 4;

  const int lr = lane >> 3;
  const int swz8 = ((lane & 7) ^ lr) << 3;
  const _Float16* Ag  = A  + (size_t)(m0 + w * 32 + lr) * K + swz8;
  const _Float16* B0g = B0 + (size_t)(n0 + w * 16 + lr) * K + swz8;
  const _Float16* B1g = B1 + (size_t)(n0 + w * 16 + lr) * K + swz8;

  const int qs8 = (quad ^ (l16 & 3)) << 3;
  const int kxo = ((l16 >> 2) & 1) << 5;
  int aoff[4], boff[4];
#pragma unroll
  for (int i = 0; i < 4; i++) {
    aoff[i] = (wm + i * 16 + l16) * 64 + qs8;
    boff[i] = (wn + i * 16 + l16) * 64 + qs8;
  }

  f4 acc0[4][4], acc1[4][4];
#pragma unroll
  for (int i = 0; i < 4; i++)
#pragma unroll
    for (int j = 0; j < 4; j++) {
      acc0[i][j][0] = 0.f; acc0[i][j][1] = 0.f; acc0[i][j][2] = 0.f; acc0[i][j][3] = 0.f;
      acc1[i][j][0] = 0.f; acc1[i][j][1] = 0.f; acc1[i][j][2] = 0.f; acc1[i][j][3] = 0.f;
    }

#define SA(b, kt, c)  g2l16(Ag  + (size_t)(c) * 8 * K + (size_t)(kt) * 64, \
                            &As[b][(w * 32 + (c) * 8) * 64])
#define SB0(b, kt, c) g2l16(B0g + (size_t)(c) * 8 * K + (size_t)(kt) * 64, \
                            &B0s[b][(w * 16 + (c) * 8) * 64])
#define SB1(b, kt, c) g2l16(B1g + (size_t)(c) * 8 * K + (size_t)(kt) * 64, \
                            &B1s[b][(w * 16 + (c) * 8) * 64])

  // prologue: A0 (4), B0-tile0 (2), B1-tile0 (2), A1 (4).
  // vmcnt(4): retires A0 + Btile0; A1 (4) stays in flight.
  SA(0, 0, 0); SA(0, 0, 1); SA(0, 0, 2); SA(0, 0, 3);
  SB0(0, 0, 0); SB0(0, 0, 1); SB1(0, 0, 0); SB1(0, 0, 1);
  SA(1, 1, 0); SA(1, 1, 1); SA(1, 1, 2); SA(1, 1, 3);
  asm volatile("s_waitcnt vmcnt(4)" ::: "memory");
  BAR();

  const int nt = K >> 6;
  for (int kt = 0; kt < nt; ++kt) {
    const int ca = kt % 3, na = (kt + 2) % 3;
    const int cb = kt & 1, nbb = (kt + 1) & 1;
    const bool pfA = (kt + 2) < nt;
    const bool pfB = (kt + 1) < nt;
    const _Float16* Ab  = As[ca];
    const _Float16* Bb0 = B0s[cb];
    const _Float16* Bb1 = B1s[cb];
    h8 af[4][2], b0f[4][2], b1f[4][2];
    // ---- P1: read af(8) + b0f ni0-1(4); stage B0(kt+1); MFMA acc0 ni0-1 ----
#pragma unroll
    for (int i = 0; i < 4; i++) {
      af[i][0] = *(const h8*)&Ab[aoff[i] + kxo];
      af[i][1] = *(const h8*)&Ab[aoff[i] + (kxo ^ 32)];
    }
#pragma unroll
    for (int i = 0; i < 2; i++) {
      b0f[i][0] = *(const h8*)&Bb0[boff[i] + kxo];
      b0f[i][1] = *(const h8*)&Bb0[boff[i] + (kxo ^ 32)];
    }
    if (pfB) { SB0(nbb, kt + 1, 0); SB0(nbb, kt + 1, 1); }
    BAR();
    __builtin_amdgcn_s_setprio(1);
#pragma unroll
    for (int mi = 0; mi < 4; mi++)
#pragma unroll
      for (int ni = 0; ni < 2; ni++)
#pragma unroll
        for (int ks = 0; ks < 2; ks++)
          acc0[mi][ni] = __builtin_amdgcn_mfma_f32_16x16x32_f16(
              af[mi][ks], b0f[ni][ks], acc0[mi][ni], 0, 0, 0);
    __builtin_amdgcn_s_setprio(0);
    BAR();
    // ---- P2: read b0f ni2-3(4); stage B1(kt+1); MFMA acc0 ni2-3 ----
#pragma unroll
    for (int i = 2; i < 4; i++) {
      b0f[i][0] = *(const h8*)&Bb0[boff[i] + kxo];
      b0f[i][1] = *(const h8*)&Bb0[boff[i] + (kxo ^ 32)];
    }
    if (pfB) { SB1(nbb, kt + 1, 0); SB1(nbb, kt + 1, 1); }
    BAR();
    __builtin_amdgcn_s_setprio(1);
#pragma unroll
    for (int mi = 0; mi < 4; mi++)
#pragma unroll
      for (int ni = 2; ni < 4; ni++)
#pragma unroll
        for (int ks = 0; ks < 2; ks++)
          acc0[mi][ni] = __builtin_amdgcn_mfma_f32_16x16x32_f16(
              af[mi][ks], b0f[ni][ks], acc0[mi][ni], 0, 0, 0);
    __builtin_amdgcn_s_setprio(0);
    BAR();
    // ---- P3: read b1f ni0-1(4); stage A(kt+2) half; MFMA acc1 ni0-1 ----
#pragma unroll
    for (int i = 0; i < 2; i++) {
      b1f[i][0] = *(const h8*)&Bb1[boff[i] + kxo];
      b1f[i][1] = *(const h8*)&Bb1[boff[i] + (kxo ^ 32)];
    }
    if (pfA) { SA(na, kt + 2, 0); SA(na, kt + 2, 1); }
    BAR();
    __builtin_amdgcn_s_setprio(1);
#pragma unroll
    for (int mi = 0; mi < 4; mi++)
#pragma unroll
      for (int ni = 0; ni < 2; ni++)
#pragma unroll
        for (int ks = 0; ks < 2; ks++)
          acc1[mi][ni] = __builtin_amdgcn_mfma_f32_16x16x32_f16(
              af[mi][ks], b1f[ni][ks], acc1[mi][ni], 0, 0, 0);
    __builtin_amdgcn_s_setprio(0);
    BAR();
    // ---- P4: read b1f ni2-3(4); stage A(kt+2) half; MFMA acc1 ni2-3 ----
#pragma unroll
    for (int i = 2; i < 4; i++) {
      b1f[i][0] = *(const h8*)&Bb1[boff[i] + kxo];
      b1f[i][1] = *(const h8*)&Bb1[boff[i] + (kxo ^ 32)];
    }
    if (pfA) { SA(na, kt + 2, 2); SA(na, kt + 2, 3); }
    BAR();
    __builtin_amdgcn_s_setprio(1);
#pragma unroll
    for (int mi = 0; mi < 4; mi++)
#pragma unroll
      for (int ni = 2; ni < 4; ni++)
#pragma unroll
        for (int ks = 0; ks < 2; ks++)
          acc1[mi][ni] = __builtin_amdgcn_mfma_f32_16x16x32_f16(
              af[mi][ks], b1f[ni][ks], acc1[mi][ni], 0, 0, 0);
    __builtin_amdgcn_s_setprio(0);
    // counted end-of-iter wait: A(kt+2) (4 loads) stays in flight.
    if (pfA)      asm volatile("s_waitcnt vmcnt(4)" ::: "memory");
    else if (pfB) asm volatile("s_waitcnt vmcnt(0)" ::: "memory");
    BAR();
  }
#undef SA
#undef SB0
#undef SB1

#pragma unroll
  for (int mi = 0; mi < 4; mi++)
#pragma unroll
    for (int ni = 0; ni < 4; ni++)
#pragma unroll
      for (int r = 0; r < 4; r++) {
        const int rg = m0 + wm + mi * 16 + quad * 4 + r;
        const int cg = n0 + wn + ni * 16 + l16;
        act[(size_t)rg * Nc + cg] =
            (_Float16)(gelu_fast(acc0[mi][ni][r]) * acc1[mi][ni][r]);
      }
}

// ------------- transpose + cast f32 [R,C] -> fp16 [C,R], per-z slab --------
__global__ __launch_bounds__(256) void transpose_cast_kernel(
    const float* __restrict__ in, _Float16* __restrict__ out,
    int R, int C, size_t in_zstride, size_t out_zstride) {
  __shared__ float tile[64][65];
  const float* ip = in + blockIdx.z * in_zstride;
  _Float16* op = out + blockIdx.z * out_zstride;
  const int cb = blockIdx.x * 64, rb = blockIdx.y * 64;
  const int tx = threadIdx.x & 15, ty = threadIdx.x >> 4;
#pragma unroll
  for (int i = 0; i < 4; i++) {
    f4 v = *(const f4*)&ip[(size_t)(rb + ty + 16 * i) * C + cb + tx * 4];
    tile[ty + 16 * i][tx * 4 + 0] = v[0];
    tile[ty + 16 * i][tx * 4 + 1] = v[1];
    tile[ty + 16 * i][tx * 4 + 2] = v[2];
    tile[ty + 16 * i][tx * 4 + 3] = v[3];
  }
  __syncthreads();
#pragma unroll
  for (int i = 0; i < 4; i++) {
    const int c = ty + 16 * i;
    h4 o;
#pragma unroll
    for (int j = 0; j < 4; j++) o[j] = (_Float16)tile[tx * 4 + j][c];
    *(h4*)&op[(size_t)(cb + c) * R + rb + tx * 4] = o;
  }
}

// ----------------------------- f32 -> fp16 cast ----------------------------
__global__ void cast_fp16_kernel(const float* __restrict__ in,
                                 _Float16* __restrict__ out, int n4) {
  int i = blockIdx.x * 256 + threadIdx.x;
  if (i < n4) {
    f4 v = ((const f4*)in)[i];
    h4 o;
    o[0] = (_Float16)v[0]; o[1] = (_Float16)v[1];
    o[2] = (_Float16)v[2]; o[3] = (_Float16)v[3];
    ((h4*)out)[i] = o;
  }
}

// -------------------- RMS-norm over 2048-row -> fp16 out -------------------
__global__ __launch_bounds__(256) void rmsnorm_fp16_kernel(
    const float* __restrict__ in, const float* __restrict__ scale,
    _Float16* __restrict__ out) {
  __shared__ float sbuf[4];
  const int row = blockIdx.x, tid = threadIdx.x;
  const float* r = in + (size_t)row * 2048;
  f4 a = ((const f4*)r)[tid];
  f4 b = ((const f4*)r)[tid + 256];
  float ss = a[0]*a[0] + a[1]*a[1] + a[2]*a[2] + a[3]*a[3] +
             b[0]*b[0] + b[1]*b[1] + b[2]*b[2] + b[3]*b[3];
  float tot = block_sum(ss, sbuf);
  float rs = rsqrtf(tot * (1.f / 2048.f) + 1e-6f);
  f4 s0 = ((const f4*)scale)[tid];
  f4 s1 = ((const f4*)scale)[tid + 256];
  h4 o0, o1;
#pragma unroll
  for (int j = 0; j < 4; j++) {
    o0[j] = (_Float16)(a[j] * rs * (1.f + s0[j]));
    o1[j] = (_Float16)(b[j] * rs * (1.f + s1[j]));
  }
  ((h4*)(out + (size_t)row * 2048))[tid] = o0;
  ((h4*)(out + (size_t)row * 2048))[tid + 256] = o1;
}

// --- fused per-head norm/RoPE over combined qkv rows (fp16 in, fp16 out) ---
__global__ __launch_bounds__(256) void headnorm_qkv_kernel(
    const _Float16* __restrict__ qkv, _Float16* __restrict__ out,
    const float* __restrict__ qsc, const float* __restrict__ ksc,
    const int* __restrict__ pos_arr) {
  const int inst = blockIdx.x * 4 + (threadIdx.x >> 6);
  const int lane = threadIdx.x & 63;
  const int row = inst >> 4, slot = inst & 15;
  const _Float16* r = qkv + (size_t)row * QS + slot * 256;
  h4 vh = ((const h4*)r)[lane];
  f4 v;
#pragma unroll
  for (int j = 0; j < 4; j++) v[j] = (float)vh[j];
  float ss = v[0]*v[0] + v[1]*v[1] + v[2]*v[2] + v[3]*v[3];
#pragma unroll
  for (int off = 32; off; off >>= 1) ss += __shfl_xor(ss, off, 64);
  const float rs = rsqrtf(ss * (1.f / 256.f) + 1e-6f);
  const float* scale = (slot < 8) ? qsc : (slot < 12 ? ksc : nullptr);
  f4 nv;
  if (scale) {
    f4 sc = ((const f4*)scale)[lane];
#pragma unroll
    for (int j = 0; j < 4; j++) nv[j] = v[j] * rs * (1.f + sc[j]);
  } else {
#pragma unroll
    for (int j = 0; j < 4; j++) nv[j] = v[j] * rs;
  }
  h4 res;
  if (slot < 12) {  // rope for q and k
    const float pos = (float)pos_arr[row];
    const bool lo = lane < 32;
#pragma unroll
    for (int j = 0; j < 4; j++) {
      float partner = __shfl_xor(nv[j], 32, 64);
      const int ph = (lane * 4 + j) & 127;
      float it = exp2f((float)ph * -0.103810253f);  // 10000^(-p/128)
      float ang = pos * it;
      float sn, cs;
      sincosf(ang, &sn, &cs);
      res[j] = (_Float16)(lo ? (nv[j] * cs - partner * sn)
                             : (nv[j] * cs + partner * sn));
    }
  } else {
#pragma unroll
    for (int j = 0; j < 4; j++) res[j] = (_Float16)nv[j];
  }
  ((h4*)(out + (size_t)row * QS + slot * 256))[lane] = res;
}

// ---- transpose V slots of qkvh: [row][3072+kvh*256+h] -> vT[b,kvh,h,t] ----
__global__ __launch_bounds__(256) void transpose_v_kernel(
    const _Float16* __restrict__ qkvh, _Float16* __restrict__ vT) {
  __shared__ _Float16 tile[32][33];
  const int z = blockIdx.z;
  const int b = z >> 2, kvh = z & 3;
  const int tb = blockIdx.x * 32, hb = blockIdx.y * 32;
  const int x = threadIdx.x, y = threadIdx.y;
#pragma unroll
  for (int i = 0; i < 4; i++)
    tile[y + 8 * i][x] =
        qkvh[(size_t)(b * TDIM + tb + y + 8 * i) * QS + 3072 + kvh * 256 + hb + x];
  __syncthreads();
#pragma unroll
  for (int i = 0; i < 4; i++)
    vT[((size_t)z * HDIM + hb + y + 8 * i) * TDIM + tb + x] = tile[x][y + 8 * i];
}

// --------------------- flash attention, 64 q-rows / block ------------------
// Ks [32][256]h and Vs [256][32]h XOR-chunk-swizzled (R5-verified).
__global__ __launch_bounds__(256) void attn_kernel(
    const _Float16* __restrict__ qkvh, const _Float16* __restrict__ vT,
    _Float16* __restrict__ enc) {
  __shared__ _Float16 Ks[32 * 256];
  __shared__ _Float16 Vs[256 * 32];
  __shared__ _Float16 Ps[4][16 * 32];
  const int t0 = blockIdx.x * 64;
  const int n = blockIdx.y;
  const int b = blockIdx.z;
  const int kvh = n >> 1;
  const int tid = threadIdx.x;
  const int w = tid >> 6, lane = tid & 63, l16 = lane & 15, quad = lane >> 4;
  const int kxr = (l16 >> 2) & 1;                  // Ks ks-plane phys xor
  const int qsK8 = (quad ^ (l16 & 3)) << 3;        // Ks chunk swizzle (halves)
  const int qsV8 = (quad ^ ((l16 >> 1) & 3)) << 3; // Vs chunk swizzle (halves)

  h8 qfrag[8];
  {
    const int trow = t0 + w * 16 + l16;
    const _Float16* qp =
        qkvh + (size_t)(b * TDIM + trow) * QS + n * HDIM + quad * 8;
#pragma unroll
    for (int ks = 0; ks < 8; ks++) qfrag[ks] = *(const h8*)(qp + ks * 32);
  }

  f4 O[16];
#pragma unroll
  for (int i = 0; i < 16; i++) { O[i][0] = 0.f; O[i][1] = 0.f; O[i][2] = 0.f; O[i][3] = 0.f; }
  float m_i[4], l_i[4];
#pragma unroll
  for (int r = 0; r < 4; r++) { m_i[r] = -1e30f; l_i[r] = 0.f; }

  int s_begin = t0 - (WINDOW - 1);
  if (s_begin < 0) s_begin = 0;
  s_begin &= ~31;
  const int s_end = t0 + 64;
  const _Float16* kbase = qkvh + (size_t)b * TDIM * QS + 2048 + kvh * HDIM;
  const _Float16* vbase = vT + ((size_t)(b * NKV + kvh) * HDIM) * TDIM;

  for (int s0 = s_begin; s0 < s_end; s0 += 32) {
    __syncthreads();
#pragma unroll
    for (int p = 0; p < 4; p++) {
      int g = p * 256 + tid;
      {
        int si = g >> 5, c = g & 31;
        *(h8*)&Ks[si * 256 + ((c ^ (si & 7)) << 3)] =
            *(const h8*)(kbase + (size_t)(s0 + si) * QS + (c << 3));
      }
      {
        int h = g >> 2, c = g & 3;
        *(h8*)&Vs[h * 32 + ((c ^ ((g >> 3) & 3)) << 3)] =
            *(const h8*)(vbase + (size_t)h * TDIM + s0 + (c << 3));
      }
    }
    __syncthreads();

    float P[2][4], cmax[4];
#pragma unroll
    for (int r = 0; r < 4; r++) cmax[r] = -1e30f;
#pragma unroll
    for (int sc = 0; sc < 2; sc++) {
      f4 lg; lg[0] = 0.f; lg[1] = 0.f; lg[2] = 0.f; lg[3] = 0.f;
#pragma unroll
      for (int ks = 0; ks < 8; ks++) {
        h8 kb = *(const h8*)&Ks[(sc * 16 + l16) * 256 + ((ks ^ kxr) << 5) + qsK8];
        lg = __builtin_amdgcn_mfma_f32_16x16x32_f16(qfrag[ks], kb, lg, 0, 0, 0);
      }
      const int scol = s0 + sc * 16 + l16;
#pragma unroll
      for (int r = 0; r < 4; r++) {
        const int trow = t0 + w * 16 + quad * 4 + r;
        // 50*tanh(lg/50): tanh(y)=(e^2y-1)/(e^2y+1), e^2y = expf(lg*0.04)
        float t = __expf(lg[r] * 0.04f);
        float xv = 50.f - 100.f * __builtin_amdgcn_rcpf(t + 1.f);
        bool valid = (scol <= trow) && (scol > trow - WINDOW);
        P[sc][r] = valid ? xv : -1e30f;
        cmax[r] = fmaxf(cmax[r], P[sc][r]);
      }
    }
#pragma unroll
    for (int off = 1; off < 16; off <<= 1)
#pragma unroll
      for (int r = 0; r < 4; r++) cmax[r] = fmaxf(cmax[r], __shfl_xor(cmax[r], off, 16));
    float alpha[4], psum[4];
#pragma unroll
    for (int r = 0; r < 4; r++) {
      float mnew = fmaxf(m_i[r], cmax[r]);
      alpha[r] = __expf(m_i[r] - mnew);
      m_i[r] = mnew;
      psum[r] = 0.f;
    }
#pragma unroll
    for (int sc = 0; sc < 2; sc++)
#pragma unroll
      for (int r = 0; r < 4; r++) {
        float pv = __expf(P[sc][r] - m_i[r]);
        P[sc][r] = pv;
        psum[r] += pv;
      }
#pragma unroll
    for (int off = 1; off < 16; off <<= 1)
#pragma unroll
      for (int r = 0; r < 4; r++) psum[r] += __shfl_xor(psum[r], off, 16);
#pragma unroll
    for (int r = 0; r < 4; r++) l_i[r] = l_i[r] * alpha[r] + psum[r];
#pragma unroll
    for (int i = 0; i < 16; i++)
#pragma unroll
      for (int r = 0; r < 4; r++) O[i][r] *= alpha[r];
#pragma unroll
    for (int sc = 0; sc < 2; sc++)
#pragma unroll
      for (int r = 0; r < 4; r++)
        Ps[w][(quad * 4 + r) * 32 + sc * 16 + l16] = (_Float16)P[sc][r];
    h8 pa = *(const h8*)&Ps[w][l16 * 32 + quad * 8];
#pragma unroll
    for (int ht = 0; ht < 16; ht++) {
      h8 vb = *(const h8*)&Vs[(ht * 16 + l16) * 32 + qsV8];
      O[ht] = __builtin_amdgcn_mfma_f32_16x16x32_f16(pa, vb, O[ht], 0, 0, 0);
    }
  }

  float invl[4];
#pragma unroll
  for (int r = 0; r < 4; r++) invl[r] = 1.f / l_i[r];
#pragma unroll
  for (int ht = 0; ht < 16; ht++)
#pragma unroll
    for (int r = 0; r < 4; r++) {
      const int trow = t0 + w * 16 + quad * 4 + r;
      enc[((size_t)(b * TDIM + trow)) * (NQ * HDIM) + n * HDIM + ht * 16 + l16] =
          (_Float16)(O[ht][r] * invl[r]);
    }
}

// ------ post-attn: residual + norm, then pre-FFW norm (fused) --------------
__global__ __launch_bounds__(256) void postattn_kernel(
    const float* __restrict__ attnraw, const float* __restrict__ x,
    const float* __restrict__ post_scale, const float* __restrict__ pre_ffw_scale,
    const float* __restrict__ skip, float* __restrict__ attn_out,
    _Float16* __restrict__ ffw_in) {
  __shared__ float sbuf[4];
  const int row = blockIdx.x, tid = threadIdx.x;
  const float* ar = attnraw + (size_t)row * 2048;
  const float* xr = x + (size_t)row * 2048;
  f4 a0 = ((const f4*)ar)[tid], a1 = ((const f4*)ar)[tid + 256];
  float ss = a0[0]*a0[0] + a0[1]*a0[1] + a0[2]*a0[2] + a0[3]*a0[3] +
             a1[0]*a1[0] + a1[1]*a1[1] + a1[2]*a1[2] + a1[3]*a1[3];
  float tot = block_sum(ss, sbuf);
  float rs = rsqrtf(tot * (1.f / 2048.f) + 1e-6f);
  const float sk = skip[0];
  f4 x0 = ((const f4*)xr)[tid], x1 = ((const f4*)xr)[tid + 256];
  f4 p0 = ((const f4*)post_scale)[tid], p1 = ((const f4*)post_scale)[tid + 256];
  f4 at0, at1;
#pragma unroll
  for (int j = 0; j < 4; j++) {
    at0[j] = x0[j] * sk + a0[j] * rs * (1.f + p0[j]);
    at1[j] = x1[j] * sk + a1[j] * rs * (1.f + p1[j]);
  }
  ((f4*)(attn_out + (size_t)row * 2048))[tid] = at0;
  ((f4*)(attn_out + (size_t)row * 2048))[tid + 256] = at1;
  float ss2 = at0[0]*at0[0] + at0[1]*at0[1] + at0[2]*at0[2] + at0[3]*at0[3] +
              at1[0]*at1[0] + at1[1]*at1[1] + at1[2]*at1[2] + at1[3]*at1[3];
  float tot2 = block_sum(ss2, sbuf);
  float rs2 = rsqrtf(tot2 * (1.f / 2048.f) + 1e-6f);
  f4 f0 = ((const f4*)pre_ffw_scale)[tid], f1 = ((const f4*)pre_ffw_scale)[tid + 256];
  h4 o0, o1;
#pragma unroll
  for (int j = 0; j < 4; j++) {
    o0[j] = (_Float16)(at0[j] * rs2 * (1.f + f0[j]));
    o1[j] = (_Float16)(at1[j] * rs2 * (1.f + f1[j]));
  }
  ((h4*)(ffw_in + (size_t)row * 2048))[tid] = o0;
  ((h4*)(ffw_in + (size_t)row * 2048))[tid + 256] = o1;
}

// ------ final: out = attn_out + rmsnorm(ffw_fp16, post_ffw_scale) ----------
__global__ __launch_bounds__(256) void final_kernel(
    const _Float16* __restrict__ ffw, const float* __restrict__ attn_out,
    const float* __restrict__ post_ffw_scale, float* __restrict__ out) {
  __shared__ float sbuf[4];
  const int row = blockIdx.x, tid = threadIdx.x;
  const _Float16* fr = ffw + (size_t)row * 2048;
  const float* ar = attn_out + (size_t)row * 2048;
  h4 fh0 = ((const h4*)fr)[tid], fh1 = ((const h4*)fr)[tid + 256];
  f4 a0, a1;
#pragma unroll
  for (int j = 0; j < 4; j++) { a0[j] = (float)fh0[j]; a1[j] = (float)fh1[j]; }
  float ss = a0[0]*a0[0] + a0[1]*a0[1] + a0[2]*a0[2] + a0[3]*a0[3] +
             a1[0]*a1[0] + a1[1]*a1[1] + a1[2]*a1[2] + a1[3]*a1[3];
  float tot = block_sum(ss, sbuf);
  float rs = rsqrtf(tot * (1.f / 2048.f) + 1e-6f);
  f4 s0 = ((const f4*)post_ffw_scale)[tid], s1 = ((const f4*)post_ffw_scale)[tid + 256];
  f4 x0 = ((const f4*)ar)[tid], x1 = ((const f4*)ar)[tid + 256];
  f4 o0, o1;
#pragma unroll
  for (int j = 0; j < 4; j++) {
    o0[j] = x0[j] + a0[j] * rs * (1.f + s0[j]);
    o1[j] = x1[j] + a1[j] * rs * (1.f + s1[j]);
  }
  ((f4*)(out + (size_t)row * 2048))[tid] = o0;
  ((f4*)(out + (size_t)row * 2048))[tid + 256] = o1;
}

// ---------------------------------------------------------------------------
extern "C" void kernel_launch(void* const* d_in, const int* in_sizes, int n_in,
                              void* d_out, int out_size, void* d_ws, size_t ws_size,
                              hipStream_t stream) {
  (void)in_sizes; (void)n_in; (void)out_size; (void)ws_size;
  const float* x              = (const float*)d_in[0];
  const int*   segment_pos    = (const int*)d_in[1];
  const float* w_q            = (const float*)d_in[7];
  const float* w_kv           = (const float*)d_in[8];
  const float* w_attn_vec     = (const float*)d_in[9];
  const float* q_norm_scale   = (const float*)d_in[10];
  const float* k_norm_scale   = (const float*)d_in[11];
  const float* pre_attn_scale = (const float*)d_in[12];
  const float* post_attn_scale= (const float*)d_in[13];
  const float* pre_ffw_scale  = (const float*)d_in[14];
  const float* post_ffw_scale = (const float*)d_in[15];
  const float* w_gating       = (const float*)d_in[16];
  const float* w_linear       = (const float*)d_in[17];
  const float* skip_scale     = (const float*)d_in[18];

  char* ws = (char*)d_ws;
  const size_t MB = 1024 * 1024;
  // weight arena [0,64MB): Wqkv (16MB) -> Wo (8MB) -> Wg (64MB) -> Wl (32MB)
  _Float16* Wqkv  = (_Float16*)(ws + 0);
  _Float16* Wo    = (_Float16*)(ws + 0);
  _Float16* Wg    = (_Float16*)(ws + 0);
  _Float16* Wl    = (_Float16*)(ws + 0);
  _Float16* Hbf   = (_Float16*)(ws + 64 * MB);   // 16MB: h, later ffw_in
  float* attnF    = (float*)(ws + 80 * MB);      // 32MB residual
  _Float16* qkvraw= (_Float16*)(ws + 112 * MB);  // 32MB [4096][4096] fp16
  _Float16* qkvh  = (_Float16*)(ws + 144 * MB);  // 32MB
  _Float16* enc   = (_Float16*)(ws + 176 * MB);  // 16MB
  float* attnraw  = (float*)(ws + 192 * MB);     // 32MB
  _Float16* vT    = (_Float16*)(ws + 224 * MB);  //  8MB
  _Float16* act   = (_Float16*)(ws + 112 * MB);  // 64MB (qkvraw/qkvh dead)
  _Float16* ffw   = (_Float16*)(ws + 192 * MB);  // 16MB (attnraw dead)
  float* outp     = (float*)d_out;

  // --- weight prep: per-head [D,H]->[H,D], stacked q|k|v into Wqkv ---
  transpose_cast_kernel<<<dim3(HDIM / 64, DDIM / 64, NQ), 256, 0, stream>>>(
      w_q, Wqkv, DDIM, HDIM, (size_t)DDIM * HDIM, (size_t)HDIM * DDIM);
  transpose_cast_kernel<<<dim3(HDIM / 64, DDIM / 64, NKV), 256, 0, stream>>>(
      w_kv, Wqkv + (size_t)2048 * DDIM, DDIM, HDIM,
      (size_t)DDIM * HDIM, (size_t)HDIM * DDIM);
  transpose_cast_kernel<<<dim3(HDIM / 64, DDIM / 64, NKV), 256, 0, stream>>>(
      w_kv + (size_t)NKV * DDIM * HDIM, Wqkv + (size_t)3072 * DDIM, DDIM, HDIM,
      (size_t)DDIM * HDIM, (size_t)HDIM * DDIM);
  // --- h = rmsnorm(x, pre_attn_scale) ---
  rmsnorm_fp16_kernel<<<MROWS, 256, 0, stream>>>(x, pre_attn_scale, Hbf);
  // --- fused QKV projection (fp16 out): 512 wgs ---
  gemm256<1><<<dim3((QS / 128) * (MROWS / 256)), 512, 0, stream>>>(
      Hbf, Wqkv, qkvraw, MROWS, QS, DDIM);
  // --- fused per-head norms + RoPE over all 16 head-slots ---
  headnorm_qkv_kernel<<<(MROWS * 16) / 4, 256, 0, stream>>>(
      qkvraw, qkvh, q_norm_scale, k_norm_scale, segment_pos);
  transpose_v_kernel<<<dim3(TDIM / 32, HDIM / 32, BDIM * NKV), dim3(32, 8), 0, stream>>>(
      qkvh, vT);
  // --- attention ---
  attn_kernel<<<dim3(TDIM / 64, NQ, BDIM), 256, 0, stream>>>(qkvh, vT, enc);
  // --- output projection: 256 wgs ---
  transpose_cast_kernel<<<dim3(DDIM / 64, (NQ * HDIM) / 64, 1), 256, 0, stream>>>(
      w_attn_vec, Wo, NQ * HDIM, DDIM, 0, 0);
  gemm256<0><<<dim3((DDIM / 128) * (MROWS / 256)), 512, 0, stream>>>(
      enc, Wo, attnraw, MROWS, DDIM, NQ * HDIM);
  // --- post-attn norm + residual, pre-FFW norm ---
  postattn_kernel<<<MROWS, 256, 0, stream>>>(attnraw, x, post_attn_scale,
                                             pre_ffw_scale, skip_scale, attnF, Hbf);
  // --- FFN: fused dual-gating GEMM, 256x128 tile, mixed-depth pipeline ---
  cast_fp16_kernel<<<(2 * FDIM * DDIM / 4 + 255) / 256, 256, 0, stream>>>(
      w_gating, Wg, 2 * FDIM * DDIM / 4);
  gemm_gate256<<<dim3((FDIM / 128) * (MROWS / 256)), 512, 0, stream>>>(
      Hbf, Wg, Wg + (size_t)FDIM * DDIM, act, MROWS, FDIM, DDIM);
  // --- linear (fp16 out): 256 wgs ---
  transpose_cast_kernel<<<dim3(DDIM / 64, FDIM / 64, 1), 256, 0, stream>>>(
      w_linear, Wl, FDIM, DDIM, 0, 0);
  gemm256<1><<<dim3((DDIM / 128) * (MROWS / 256)), 512, 0, stream>>>(
      act, Wl, ffw, MROWS, DDIM, FDIM);
  // --- final norm + residual ---
  final_kernel<<<MROWS, 256, 0, stream>>>(ffw, attnF, post_ffw_scale, outp);
}